// Round 14
// baseline (378.280 us; speedup 1.0000x reference)
//
#include <hip/hip_runtime.h>
#include <math.h>

#define N_HEADC  16
#define D_MODELC 1024
#define ATTN_N_C    3145728
#define ATTN_PAD_C  4194304
#define ATTN_NC     2097152   // half-size complex FFT length (2^21 = 8^7)
#define ATTN_KEEP_C 524288
#define PROJ_N_C    1048576
#define PROJ_PAD_C  1048576
#define PROJ_NC     524288    // 2^19 = 2 * 8^6
#define PROJ_KEEP_C 131072
#define BATCH_C 2
#define SEQ_C   2048

typedef __attribute__((ext_vector_type(8))) short s16x8;
typedef __attribute__((ext_vector_type(4))) float f32x4;

#define AS1U(p) ((const __attribute__((address_space(1))) uint*)(p))
#define AS3U(p) ((__attribute__((address_space(3))) uint*)(p))

static __device__ __forceinline__ ushort f2bf(float f) {
    __bf16 b = (__bf16)f;
    return __builtin_bit_cast(ushort, b);
}
static __device__ __forceinline__ float bf2f(ushort u) {
    return __builtin_bit_cast(float, ((uint)u) << 16);
}
static __device__ __forceinline__ float2 cmul(float2 a, float2 b) {
    return make_float2(a.x * b.x - a.y * b.y, a.x * b.y + a.y * b.x);
}
static __device__ __forceinline__ float2 cadd(float2 a, float2 b) {
    return make_float2(a.x + b.x, a.y + b.y);
}
static __device__ __forceinline__ float2 csub(float2 a, float2 b) {
    return make_float2(a.x - b.x, a.y - b.y);
}
static __device__ __forceinline__ float2 crot(float2 z) {   // i*z
    return make_float2(-z.y, z.x);
}

// 8-point inverse DFT core (verified R9). a[0..7] -> B[0..7] (pre-twiddle).
static __device__ __forceinline__ void r8core(const float2* a, float2* B) {
    const float2 t0 = cadd(a[0], a[4]), t1 = csub(a[0], a[4]);
    const float2 t2 = cadd(a[2], a[6]), t3 = csub(a[2], a[6]);
    const float2 t4 = cadd(a[1], a[5]), t5 = csub(a[1], a[5]);
    const float2 t6 = cadd(a[3], a[7]), t7 = csub(a[3], a[7]);
    const float2 E0 = cadd(t0, t2), E2 = csub(t0, t2);
    const float2 E1 = cadd(t1, crot(t3)), E3 = csub(t1, crot(t3));
    const float2 F0 = cadd(t4, t6), F2 = csub(t4, t6);
    const float2 F1 = cadd(t5, crot(t7)), F3 = csub(t5, crot(t7));
    const float c = 0.70710678118654752f;
    const float2 G1 = make_float2(c * (F1.x - F1.y), c * (F1.x + F1.y));   // c(1+i)F1
    const float2 G2 = crot(F2);                                            // iF2
    const float2 G3 = make_float2(c * (-F3.x - F3.y), c * (F3.x - F3.y));  // c(-1+i)F3
    B[0] = cadd(E0, F0); B[4] = csub(E0, F0);
    B[1] = cadd(E1, G1); B[5] = csub(E1, G1);
    B[2] = cadd(E2, G2); B[6] = csub(E2, G2);
    B[3] = cadd(E3, G3); B[7] = csub(E3, G3);
}

// ---------------------------------------------------------------------------
// Scatter kept coeffs into zeroed HALF spectrum H[0..Nc].
// ---------------------------------------------------------------------------
__global__ void scatter_half(const float* __restrict__ re, const float* __restrict__ im,
                             const int* __restrict__ idx, float2* __restrict__ H, int keep) {
    int t = blockIdx.x * blockDim.x + threadIdx.x;
    if (t >= keep) return;
    H[idx[t]] = make_float2(re[t], im[t]);
}

// ---------------------------------------------------------------------------
// Pack half-spectrum H (len Nc+1) into Z (len Nc) for half-size complex iFFT.
// ---------------------------------------------------------------------------
__global__ void pack_z(const float2* __restrict__ H, float2* __restrict__ Z,
                       int Nc, float th0) {
    int k = blockIdx.x * blockDim.x + threadIdx.x;
    if (k >= Nc) return;
    float2 g = H[k];
    float2 hm = H[Nc - k];
    if (k == 0) { g.y = 0.f; hm.y = 0.f; }
    float2 gh = make_float2(hm.x, -hm.y);
    float2 sum = make_float2(g.x + gh.x, g.y + gh.y);
    float2 dif = make_float2(g.x - gh.x, g.y - gh.y);
    float si, co;
    __sincosf(th0 * (float)k, &si, &co);
    float2 t = make_float2(dif.x * co - dif.y * si, dif.x * si + dif.y * co);
    Z[k] = make_float2(sum.x - t.y, sum.y + t.x);
}

// ---------------------------------------------------------------------------
// Radix-2 Stockham inverse stage (proj only: peels 2^19 -> 8^6).
// ---------------------------------------------------------------------------
__global__ void fft_stage(const float2* __restrict__ in, float2* __restrict__ out,
                          int slog, int m, int half) {
    int t = blockIdx.x * blockDim.x + threadIdx.x;
    if (t >= half) return;
    int s = 1 << slog;
    int q = t & (s - 1);
    int p = t >> slog;
    float si, co;
    __sincosf((float)(M_PI / (double)m) * (float)p, &si, &co);
    float2 a = in[q + s * p];
    float2 b = in[q + s * (p + m)];
    float2 su = cadd(a, b);
    float2 di = csub(a, b);
    int ob = q + ((s << 1) * p);
    out[ob]     = su;
    out[ob + s] = make_float2(di.x * co - di.y * si, di.x * si + di.y * co);
}

// ---------------------------------------------------------------------------
// Radix-8 Stockham inverse stage (verified R9) — used for the odd final pass.
// ---------------------------------------------------------------------------
__global__ void fft_stage_r8(const float2* __restrict__ in, float2* __restrict__ out,
                             int slog, int M, float ang0, int eighth) {
    int t = blockIdx.x * blockDim.x + threadIdx.x;
    if (t >= eighth) return;
    const int s = 1 << slog;
    const int q = t & (s - 1);
    const int p = t >> slog;
    float2 a[8];
#pragma unroll
    for (int j = 0; j < 8; ++j)
        a[j] = in[q + (size_t)s * (p + j * M)];
    float2 B[8];
    r8core(a, B);
    float si, co;
    __sincosf(ang0 * (float)p, &si, &co);
    const float2 w = make_float2(co, si);
    const int ob = q + 8 * s * p;
    out[ob] = B[0];
    float2 wj = w;
    out[ob + s] = cmul(wj, B[1]);
#pragma unroll
    for (int j = 2; j < 8; ++j) {
        wj = cmul(wj, w);
        out[ob + j * s] = cmul(wj, B[j]);
    }
}

// ---------------------------------------------------------------------------
// FUSED double radix-8 (radix-64) Stockham inverse pass (verified R12).
// ---------------------------------------------------------------------------
__global__ __launch_bounds__(256) void fft_stage_r64(
    const float2* __restrict__ in, float2* __restrict__ out, int slog, int M) {
    __shared__ float2 Ysh[32][8][9];
    const int tid = threadIdx.x;
    const int g = tid & 31, u = tid >> 5;
    const int s = 1 << slog;
    const int M8 = M >> 3;
    const int G = blockIdx.x * 32 + g;
    const int q = G & (s - 1);
    const int p0 = G >> slog;

    const int p = p0 + u * M8;
    float2 a[8];
#pragma unroll
    for (int j = 0; j < 8; ++j)
        a[j] = in[q + (size_t)s * (p + j * M)];
    float2 B[8];
    r8core(a, B);
    float si, co;
    __sincosf((0.78539816339744831f / (float)M) * (float)p, &si, &co);  // pi/(4M)*p
    const float2 w = make_float2(co, si);
    Ysh[g][u][0] = B[0];
    float2 wj = w;
    Ysh[g][u][1] = cmul(wj, B[1]);
#pragma unroll
    for (int j = 2; j < 8; ++j) {
        wj = cmul(wj, w);
        Ysh[g][u][j] = cmul(wj, B[j]);
    }
    __syncthreads();

    float2 z[8];
#pragma unroll
    for (int jp = 0; jp < 8; ++jp)
        z[jp] = Ysh[g][jp][u];
    float2 B2[8];
    r8core(z, B2);
    __sincosf((0.78539816339744831f / (float)M8) * (float)p0, &si, &co); // pi/(4*M8)*p0
    const float2 w2 = make_float2(co, si);
    const size_t ob = (size_t)q + (size_t)u * s + (size_t)64 * s * p0;
    out[ob] = B2[0];
    float2 wj2 = w2;
    out[ob + (size_t)8 * s] = cmul(wj2, B2[1]);
#pragma unroll
    for (int j2 = 2; j2 < 8; ++j2) {
        wj2 = cmul(wj2, w2);
        out[ob + (size_t)j2 * 8 * s] = cmul(wj2, B2[j2]);
    }
}

// ---------------------------------------------------------------------------
// Fused unpack + transpose + bf16 cast. x[j] = (j even ? Re : Im) z[j>>1].
// ---------------------------------------------------------------------------
__global__ __launch_bounds__(256) void transpose_wz_bf16(
    const float2* __restrict__ z, ushort* __restrict__ WT,
    int Kd, int Nd, float inv, const float* __restrict__ sc) {
    __shared__ float T[32][33];
    const int n0 = blockIdx.x * 32, k0 = blockIdx.y * 32;
    const int tx = threadIdx.x & 31, ty = threadIdx.x >> 5;
    const float s = inv * sc[0];
    for (int r = ty; r < 32; r += 8) {
        size_t j = (size_t)(k0 + r) * Nd + n0 + tx;
        float2 zz = z[j >> 1];
        T[r][tx] = (j & 1) ? zz.y : zz.x;
    }
    __syncthreads();
    for (int r = ty; r < 32; r += 8)
        WT[(size_t)(n0 + r) * Kd + k0 + tx] = f2bf(T[tx][r] * s);
}

// ---------------------------------------------------------------------------
// x (fp32) -> bf16
// ---------------------------------------------------------------------------
__global__ void x_to_bf16(const float* __restrict__ x, ushort* __restrict__ xb, int n4) {
    int i = blockIdx.x * blockDim.x + threadIdx.x;
    if (i >= n4) return;
    float4 v = *(const float4*)(x + (size_t)i * 4);
    ushort4 o;
    o.x = f2bf(v.x); o.y = f2bf(v.y); o.z = f2bf(v.z); o.w = f2bf(v.w);
    *(ushort4*)(xb + (size_t)i * 4) = o;
}

// ---------------------------------------------------------------------------
// bf16 MFMA GEMM (R11): global_load_lds width=16 staging + XOR swizzle.
// ---------------------------------------------------------------------------
template <int OUTMODE>
__global__ __launch_bounds__(256) void gemm_bt_mfma(
    const ushort* __restrict__ A, const ushort* __restrict__ Bt,
    const float* __restrict__ bias, void* __restrict__ Cout,
    ushort* __restrict__ Vt, int M, int N, int K) {
    __shared__ ushort As[128 * 32];
    __shared__ ushort Bs[128 * 32];
    const int tid = threadIdx.x;
    const int wid = tid >> 6, lane = tid & 63, quad = lane >> 4, l16 = lane & 15;
    const int row0 = blockIdx.y * 128, col0 = blockIdx.x * 128;
    const int mh = (wid >> 1) * 64, nh = (wid & 1) * 64;
    const int swz = (quad ^ (l16 & 3)) * 8;

    f32x4 acc[4][4] = {};

    for (int k0 = 0; k0 < K; k0 += 32) {
        __syncthreads();
#pragma unroll
        for (int rep = 0; rep < 2; ++rep) {
            int c = tid + rep * 256;
            int r = c >> 2;
            int kc = (c & 3) ^ (r & 3);
            ushort* lbA = &As[(rep * 256 + wid * 64) * 8];
            ushort* lbB = &Bs[(rep * 256 + wid * 64) * 8];
            __builtin_amdgcn_global_load_lds(
                AS1U(A + (size_t)(row0 + r) * K + k0 + kc * 8), AS3U(lbA), 16, 0, 0);
            __builtin_amdgcn_global_load_lds(
                AS1U(Bt + (size_t)(col0 + r) * K + k0 + kc * 8), AS3U(lbB), 16, 0, 0);
        }
        __syncthreads();
        s16x8 af[4], bfr[4];
#pragma unroll
        for (int mi = 0; mi < 4; ++mi)
            af[mi] = *(const s16x8*)&As[(mh + mi * 16 + l16) * 32 + swz];
#pragma unroll
        for (int ni = 0; ni < 4; ++ni)
            bfr[ni] = *(const s16x8*)&Bs[(nh + ni * 16 + l16) * 32 + swz];
#pragma unroll
        for (int mi = 0; mi < 4; ++mi)
#pragma unroll
            for (int ni = 0; ni < 4; ++ni)
                acc[mi][ni] = __builtin_amdgcn_mfma_f32_16x16x32_bf16(
                    af[mi], bfr[ni], acc[mi][ni], 0, 0, 0);
    }

#pragma unroll
    for (int mi = 0; mi < 4; ++mi)
#pragma unroll
        for (int ni = 0; ni < 4; ++ni) {
            const int col = col0 + nh + ni * 16 + l16;
            const int rbase = row0 + mh + mi * 16 + quad * 4;
            const float bv = bias[col];
            if (OUTMODE == 0) {
                float* C = (float*)Cout;
#pragma unroll
                for (int j = 0; j < 4; ++j)
                    C[(size_t)(rbase + j) * N + col] = acc[mi][ni][j] + bv;
            } else {
                if (col < 2048) {
                    ushort* C = (ushort*)Cout;
#pragma unroll
                    for (int j = 0; j < 4; ++j)
                        C[(size_t)(rbase + j) * N + col] = f2bf(acc[mi][ni][j] + bv);
                } else {
                    const int bb = rbase >> 11;
                    const int seq = rbase & 2047;
                    const int d = col - 2048;
                    ushort4 pk;
                    pk.x = f2bf(acc[mi][ni][0] + bv);
                    pk.y = f2bf(acc[mi][ni][1] + bv);
                    pk.z = f2bf(acc[mi][ni][2] + bv);
                    pk.w = f2bf(acc[mi][ni][3] + bv);
                    *(ushort4*)&Vt[(size_t)bb * 2097152 + (size_t)d * 2048 + seq] = pk;
                }
            }
        }
}

// ---------------------------------------------------------------------------
// MFMA flash attention, SPLIT-K v2: 128-row block shape kept (the proven
// no-scratch shape), but Q hoisted to registers (each wave only reads its
// own 32 Q-rows -> 4 x s16x8 = 16 VGPRs/lane, loaded once from global).
// Qs LDS array deleted: LDS = Ks+Vts+Ps = 36864 B -> 4 blocks/CU, and grid
// (32,16,2)=1024 = 4/CU fills it. R13 failed because LDS (55KB) capped
// residency at 2/CU — occupancy = min(grid/CU, LDS cap, VGPR cap).
// Q-hoist INCREASES live state vs R7 — opposite of the R5/R6/R10 spill
// pathology direction (shrunken 64-row state -> VGPR clamp).
// ---------------------------------------------------------------------------
__global__ __launch_bounds__(256) void attn_fwd_mfma(
    const ushort* __restrict__ qkv, const ushort* __restrict__ Vt,
    ushort* __restrict__ Op, float* __restrict__ Lp) {
    const int bx = blockIdx.x;
    const int qb = bx >> 1, split = bx & 1;
    const int h = blockIdx.y, b = blockIdx.z;
    const int tid = threadIdx.x;
    const int wid = tid >> 6, lane = tid & 63, quad = lane >> 4, l16 = lane & 15;
    const int wq = wid * 32;
    const int kt0 = split * 16;
    const float CEXP = 0.18033688011112042f;   // 0.125 * log2(e)

    __shared__ ushort Ks[64 * 72];    // [kpos][d]
    __shared__ ushort Vts[64 * 72];   // [d][kpos]
    __shared__ ushort Ps[128 * 72];   // [qrow][kpos], rows wave-private

    // Q fragments -> registers (wave-private rows wq..wq+31)
    s16x8 qf[2][2];   // [ni][ks]
#pragma unroll
    for (int ni = 0; ni < 2; ++ni)
#pragma unroll
        for (int ks = 0; ks < 2; ++ks)
            qf[ni][ks] = *(const s16x8*)(qkv +
                (size_t)(b * 2048 + qb * 128 + wq + ni * 16 + l16) * 3072 +
                h * 64 + ks * 32 + quad * 8);

    uint4 kreg[2], vreg[2];
#pragma unroll
    for (int rep = 0; rep < 2; ++rep) {
        int c = tid + rep * 256;
        int r = c >> 3, co = (c & 7) * 8;
        kreg[rep] = *(const uint4*)(qkv + (size_t)(b * 2048 + kt0 * 64 + r) * 3072 + 1024 + h * 64 + co);
        vreg[rep] = *(const uint4*)(Vt + (size_t)b * 2097152 + (size_t)(h * 64 + r) * 2048 + kt0 * 64 + co);
    }

    f32x4 o[4][2] = {};
    float l_r[2] = {0.f, 0.f};

    for (int tt = 0; tt < 16; ++tt) {
        __syncthreads();
#pragma unroll
        for (int rep = 0; rep < 2; ++rep) {
            int c = tid + rep * 256;
            int r = c >> 3, co = (c & 7) * 8;
            *(uint4*)&Ks[r * 72 + co] = kreg[rep];
            *(uint4*)&Vts[r * 72 + co] = vreg[rep];
        }
        if (tt < 15) {
            const int nt = kt0 + tt + 1;
#pragma unroll
            for (int rep = 0; rep < 2; ++rep) {
                int c = tid + rep * 256;
                int r = c >> 3, co = (c & 7) * 8;
                kreg[rep] = *(const uint4*)(qkv + (size_t)(b * 2048 + nt * 64 + r) * 3072 + 1024 + h * 64 + co);
                vreg[rep] = *(const uint4*)(Vt + (size_t)b * 2097152 + (size_t)(h * 64 + r) * 2048 + nt * 64 + co);
            }
        }
        __syncthreads();

        f32x4 s[4][2] = {};
#pragma unroll
        for (int ks = 0; ks < 2; ++ks) {
            s16x8 ka[4];
#pragma unroll
            for (int mi = 0; mi < 4; ++mi)
                ka[mi] = *(const s16x8*)&Ks[(mi * 16 + l16) * 72 + ks * 32 + quad * 8];
#pragma unroll
            for (int mi = 0; mi < 4; ++mi)
#pragma unroll
                for (int ni = 0; ni < 2; ++ni)
                    s[mi][ni] = __builtin_amdgcn_mfma_f32_16x16x32_bf16(
                        ka[mi], qf[ni][ks], s[mi][ni], 0, 0, 0);
        }

#pragma unroll
        for (int ni = 0; ni < 2; ++ni)
#pragma unroll
            for (int mi = 0; mi < 4; ++mi) {
                ushort4 pk;
#pragma unroll
                for (int j = 0; j < 4; ++j) {
                    float p = exp2f(s[mi][ni][j] * CEXP);
                    l_r[ni] += p;
                    ((ushort*)&pk)[j] = f2bf(p);
                }
                *(ushort4*)&Ps[(wq + ni * 16 + l16) * 72 + mi * 16 + quad * 4] = pk;
            }

#pragma unroll
        for (int ks = 0; ks < 2; ++ks) {
            s16x8 va[4], pb[2];
#pragma unroll
            for (int md = 0; md < 4; ++md)
                va[md] = *(const s16x8*)&Vts[(md * 16 + l16) * 72 + ks * 32 + quad * 8];
#pragma unroll
            for (int ni = 0; ni < 2; ++ni)
                pb[ni] = *(const s16x8*)&Ps[(wq + ni * 16 + l16) * 72 + ks * 32 + quad * 8];
#pragma unroll
            for (int md = 0; md < 4; ++md)
#pragma unroll
                for (int ni = 0; ni < 2; ++ni)
                    o[md][ni] = __builtin_amdgcn_mfma_f32_16x16x32_bf16(
                        va[md], pb[ni], o[md][ni], 0, 0, 0);
        }
    }

    // epilogue: write UNNORMALIZED partials.
#pragma unroll
    for (int ni = 0; ni < 2; ++ni) {
        float l = l_r[ni];
        l += __shfl_xor(l, 16);
        l += __shfl_xor(l, 32);
        const size_t row = (size_t)(b * 2048 + qb * 128 + wq + ni * 16 + l16);
        if (quad == 0)
            Lp[(size_t)split * 65536 + row * 16 + h] = l;
#pragma unroll
        for (int md = 0; md < 4; ++md) {
            ushort4 pk;
#pragma unroll
            for (int j = 0; j < 4; ++j)
                ((ushort*)&pk)[j] = f2bf(o[md][ni][j]);
            *(ushort4*)&Op[(size_t)split * 4194304 + row * 1024 + h * 64 + md * 16 + quad * 4] = pk;
        }
    }
}

// ---------------------------------------------------------------------------
// Combine the two split-K partials: ctx = (O0 + O1) / (l0 + l1).
// ---------------------------------------------------------------------------
__global__ __launch_bounds__(256) void attn_reduce(
    const ushort* __restrict__ Op, const float* __restrict__ Lp,
    ushort* __restrict__ ctx) {
    const int i = blockIdx.x * 256 + threadIdx.x;
    const size_t base = (size_t)i * 4;
    const int row = (int)(base >> 10);
    const int hh = (int)((base & 1023) >> 6);
    const float l = Lp[row * 16 + hh] + Lp[65536 + row * 16 + hh];
    const float inv = 1.f / l;
    ushort4 a = *(const ushort4*)&Op[base];
    ushort4 b = *(const ushort4*)&Op[4194304 + base];
    ushort4 o;
    o.x = f2bf((bf2f(a.x) + bf2f(b.x)) * inv);
    o.y = f2bf((bf2f(a.y) + bf2f(b.y)) * inv);
    o.z = f2bf((bf2f(a.z) + bf2f(b.z)) * inv);
    o.w = f2bf((bf2f(a.w) + bf2f(b.w)) * inv);
    *(ushort4*)&ctx[base] = o;
}

// ---------------------------------------------------------------------------
// Workspace layout (MB offsets), total 78 MB:
//   [0,16M)   A0  } reused: qkv bf16 [0,24M), Vt [24M,32M), ctx [32M,40M)
//   [16M,32M) A1  }
//   [32M,49M) H_a } dead after FFT -> Op [40M,56M), Lp [56M,57M)
//   [49M,54M) H_p
//   [54M,58M) P0   [58M,62M) P1
//   [62M,68M) WaT  [68M,70M) WpT  [70M,78M) x_bf
// ---------------------------------------------------------------------------
extern "C" void kernel_launch(void* const* d_in, const int* in_sizes, int n_in,
                              void* d_out, int out_size, void* d_ws, size_t ws_size,
                              hipStream_t stream) {
    const float* x        = (const float*)d_in[0];
    const float* attn_re  = (const float*)d_in[1];
    const float* attn_im  = (const float*)d_in[2];
    const int*   attn_idx = (const int*)d_in[3];
    const float* attn_sc  = (const float*)d_in[4];
    const float* proj_re  = (const float*)d_in[5];
    const float* proj_im  = (const float*)d_in[6];
    const int*   proj_idx = (const int*)d_in[7];
    const float* proj_sc  = (const float*)d_in[8];
    const float* attn_b   = (const float*)d_in[9];
    const float* proj_b   = (const float*)d_in[10];
    float* out = (float*)d_out;

    const size_t MB = 1048576;
    char* w = (char*)d_ws;
    float2* A0  = (float2*)(w);
    float2* A1  = (float2*)(w + 16 * MB);
    float2* Ha  = (float2*)(w + 32 * MB);
    float2* Hp  = (float2*)(w + 49 * MB);
    float2* P0  = (float2*)(w + 54 * MB);
    float2* P1  = (float2*)(w + 58 * MB);
    ushort* WaT = (ushort*)(w + 62 * MB);
    ushort* WpT = (ushort*)(w + 68 * MB);
    ushort* x_bf= (ushort*)(w + 70 * MB);
    ushort* qkvb= (ushort*)(w);
    ushort* Vt  = (ushort*)(w + 24 * MB);
    ushort* ctx = (ushort*)(w + 32 * MB);
    ushort* Op  = (ushort*)(w + 40 * MB);   // 2 x 8MB bf16 partial O
    float*  Lp  = (float*)(w + 56 * MB);    // 2 x 256KB fp32 partial l

    x_to_bf16<<<4096, 256, 0, stream>>>(x, x_bf, 1048576);

    hipMemsetAsync(Ha, 0, (size_t)(ATTN_NC + 1) * 8, stream);
    hipMemsetAsync(Hp, 0, (size_t)(PROJ_NC + 1) * 8, stream);
    scatter_half<<<ATTN_KEEP_C / 256, 256, 0, stream>>>(attn_re, attn_im, attn_idx, Ha, ATTN_KEEP_C);
    scatter_half<<<PROJ_KEEP_C / 256, 256, 0, stream>>>(proj_re, proj_im, proj_idx, Hp, PROJ_KEEP_C);

    // ---- attn iFFT: pack -> A0; 3 fused radix-64 passes + 1 radix-8 ----
    pack_z<<<ATTN_NC / 256, 256, 0, stream>>>(Ha, A0, ATTN_NC, (float)(2.0 * M_PI / ATTN_PAD_C));
    fft_stage_r64<<<(ATTN_NC / 8) / 256, 256, 0, stream>>>(A0, A1, 0,  ATTN_NC >> 3);
    fft_stage_r64<<<(ATTN_NC / 8) / 256, 256, 0, stream>>>(A1, A0, 6,  ATTN_NC >> 9);
    fft_stage_r64<<<(ATTN_NC / 8) / 256, 256, 0, stream>>>(A0, A1, 12, ATTN_NC >> 15);
    fft_stage_r8 <<<(ATTN_NC / 8) / 256, 256, 0, stream>>>(A1, A0, 18, 1,
        (float)(M_PI / 4.0), ATTN_NC / 8);
    transpose_wz_bf16<<<dim3(3072 / 32, 1024 / 32), 256, 0, stream>>>(
        A0, WaT, 1024, 3072, 1.f / ATTN_PAD_C, attn_sc);

    // ---- proj iFFT: pack -> P0; r2 + 3 fused radix-64 passes ----
    pack_z<<<PROJ_NC / 256, 256, 0, stream>>>(Hp, P0, PROJ_NC, (float)(2.0 * M_PI / PROJ_PAD_C));
    fft_stage<<<(PROJ_NC / 2) / 256, 256, 0, stream>>>(P0, P1, 0, PROJ_NC / 2, PROJ_NC / 2);
    fft_stage_r64<<<(PROJ_NC / 8) / 256, 256, 0, stream>>>(P1, P0, 1,  PROJ_NC >> 4);
    fft_stage_r64<<<(PROJ_NC / 8) / 256, 256, 0, stream>>>(P0, P1, 7,  PROJ_NC >> 10);
    fft_stage_r64<<<(PROJ_NC / 8) / 256, 256, 0, stream>>>(P1, P0, 13, PROJ_NC >> 16);
    transpose_wz_bf16<<<dim3(1024 / 32, 1024 / 32), 256, 0, stream>>>(
        P0, WpT, 1024, 1024, 1.f / PROJ_PAD_C, proj_sc);

    // qkv = x @ Wa + bias (bf16 out; V third written transposed into Vt)
    gemm_bt_mfma<1><<<dim3(3072 / 128, 4096 / 128), 256, 0, stream>>>(
        x_bf, WaT, attn_b, qkvb, Vt, 4096, 3072, 1024);

    // attention: split-K over 2 blocks (now 4 blocks/CU resident), reduce
    attn_fwd_mfma<<<dim3(SEQ_C / 64, N_HEADC, BATCH_C), 256, 0, stream>>>(qkvb, Vt, Op, Lp);
    attn_reduce<<<4096, 256, 0, stream>>>(Op, Lp, ctx);

    gemm_bt_mfma<0><<<dim3(1024 / 128, 4096 / 128), 256, 0, stream>>>(
        ctx, WpT, proj_b, out, (ushort*)nullptr, 4096, 1024, 1024);
}

// Round 15
// 366.804 us; speedup vs baseline: 1.0313x; 1.0313x over previous
//
#include <hip/hip_runtime.h>
#include <math.h>

#define N_HEADC  16
#define D_MODELC 1024
#define ATTN_N_C    3145728
#define ATTN_PAD_C  4194304
#define ATTN_NC     2097152   // half-size complex FFT length (2^21 = 8^7)
#define ATTN_KEEP_C 524288
#define PROJ_N_C    1048576
#define PROJ_PAD_C  1048576
#define PROJ_NC     524288    // 2^19 = 2 * 8^6
#define PROJ_KEEP_C 131072
#define BATCH_C 2
#define SEQ_C   2048

typedef __attribute__((ext_vector_type(8))) short s16x8;
typedef __attribute__((ext_vector_type(4))) float f32x4;

#define AS1U(p) ((const __attribute__((address_space(1))) uint*)(p))
#define AS3U(p) ((__attribute__((address_space(3))) uint*)(p))

static __device__ __forceinline__ ushort f2bf(float f) {
    __bf16 b = (__bf16)f;
    return __builtin_bit_cast(ushort, b);
}
static __device__ __forceinline__ float bf2f(ushort u) {
    return __builtin_bit_cast(float, ((uint)u) << 16);
}
static __device__ __forceinline__ float2 cmul(float2 a, float2 b) {
    return make_float2(a.x * b.x - a.y * b.y, a.x * b.y + a.y * b.x);
}
static __device__ __forceinline__ float2 cadd(float2 a, float2 b) {
    return make_float2(a.x + b.x, a.y + b.y);
}
static __device__ __forceinline__ float2 csub(float2 a, float2 b) {
    return make_float2(a.x - b.x, a.y - b.y);
}
static __device__ __forceinline__ float2 crot(float2 z) {   // i*z
    return make_float2(-z.y, z.x);
}

// 8-point inverse DFT core (verified R9). a[0..7] -> B[0..7] (pre-twiddle).
static __device__ __forceinline__ void r8core(const float2* a, float2* B) {
    const float2 t0 = cadd(a[0], a[4]), t1 = csub(a[0], a[4]);
    const float2 t2 = cadd(a[2], a[6]), t3 = csub(a[2], a[6]);
    const float2 t4 = cadd(a[1], a[5]), t5 = csub(a[1], a[5]);
    const float2 t6 = cadd(a[3], a[7]), t7 = csub(a[3], a[7]);
    const float2 E0 = cadd(t0, t2), E2 = csub(t0, t2);
    const float2 E1 = cadd(t1, crot(t3)), E3 = csub(t1, crot(t3));
    const float2 F0 = cadd(t4, t6), F2 = csub(t4, t6);
    const float2 F1 = cadd(t5, crot(t7)), F3 = csub(t5, crot(t7));
    const float c = 0.70710678118654752f;
    const float2 G1 = make_float2(c * (F1.x - F1.y), c * (F1.x + F1.y));   // c(1+i)F1
    const float2 G2 = crot(F2);                                            // iF2
    const float2 G3 = make_float2(c * (-F3.x - F3.y), c * (F3.x - F3.y));  // c(-1+i)F3
    B[0] = cadd(E0, F0); B[4] = csub(E0, F0);
    B[1] = cadd(E1, G1); B[5] = csub(E1, G1);
    B[2] = cadd(E2, G2); B[6] = csub(E2, G2);
    B[3] = cadd(E3, G3); B[7] = csub(E3, G3);
}

// ---------------------------------------------------------------------------
// Combined scatter for both half-spectra (one launch).
// ---------------------------------------------------------------------------
__global__ void scatter_half2(
    const float* __restrict__ re_a, const float* __restrict__ im_a,
    const int* __restrict__ idx_a, float2* __restrict__ Ha,
    const float* __restrict__ re_p, const float* __restrict__ im_p,
    const int* __restrict__ idx_p, float2* __restrict__ Hp) {
    int t = blockIdx.x * blockDim.x + threadIdx.x;
    if (t < ATTN_KEEP_C) {
        Ha[idx_a[t]] = make_float2(re_a[t], im_a[t]);
    } else {
        int u = t - ATTN_KEEP_C;
        Hp[idx_p[u]] = make_float2(re_p[u], im_p[u]);
    }
}

// ---------------------------------------------------------------------------
// Pack half-spectrum H (len Nc+1) into Z (len Nc) for half-size complex iFFT.
// ---------------------------------------------------------------------------
__global__ void pack_z(const float2* __restrict__ H, float2* __restrict__ Z,
                       int Nc, float th0) {
    int k = blockIdx.x * blockDim.x + threadIdx.x;
    if (k >= Nc) return;
    float2 g = H[k];
    float2 hm = H[Nc - k];
    if (k == 0) { g.y = 0.f; hm.y = 0.f; }
    float2 gh = make_float2(hm.x, -hm.y);
    float2 sum = make_float2(g.x + gh.x, g.y + gh.y);
    float2 dif = make_float2(g.x - gh.x, g.y - gh.y);
    float si, co;
    __sincosf(th0 * (float)k, &si, &co);
    float2 t = make_float2(dif.x * co - dif.y * si, dif.x * si + dif.y * co);
    Z[k] = make_float2(sum.x - t.y, sum.y + t.x);
}

// ---------------------------------------------------------------------------
// Radix-2 Stockham inverse stage (proj only: peels 2^19 -> 8^6).
// ---------------------------------------------------------------------------
__global__ void fft_stage(const float2* __restrict__ in, float2* __restrict__ out,
                          int slog, int m, int half) {
    int t = blockIdx.x * blockDim.x + threadIdx.x;
    if (t >= half) return;
    int s = 1 << slog;
    int q = t & (s - 1);
    int p = t >> slog;
    float si, co;
    __sincosf((float)(M_PI / (double)m) * (float)p, &si, &co);
    float2 a = in[q + s * p];
    float2 b = in[q + s * (p + m)];
    float2 su = cadd(a, b);
    float2 di = csub(a, b);
    int ob = q + ((s << 1) * p);
    out[ob]     = su;
    out[ob + s] = make_float2(di.x * co - di.y * si, di.x * si + di.y * co);
}

// ---------------------------------------------------------------------------
// Radix-8 Stockham inverse stage (verified R9) — odd final pass.
// ---------------------------------------------------------------------------
__global__ void fft_stage_r8(const float2* __restrict__ in, float2* __restrict__ out,
                             int slog, int M, float ang0, int eighth) {
    int t = blockIdx.x * blockDim.x + threadIdx.x;
    if (t >= eighth) return;
    const int s = 1 << slog;
    const int q = t & (s - 1);
    const int p = t >> slog;
    float2 a[8];
#pragma unroll
    for (int j = 0; j < 8; ++j)
        a[j] = in[q + (size_t)s * (p + j * M)];
    float2 B[8];
    r8core(a, B);
    float si, co;
    __sincosf(ang0 * (float)p, &si, &co);
    const float2 w = make_float2(co, si);
    const int ob = q + 8 * s * p;
    out[ob] = B[0];
    float2 wj = w;
    out[ob + s] = cmul(wj, B[1]);
#pragma unroll
    for (int j = 2; j < 8; ++j) {
        wj = cmul(wj, w);
        out[ob + j * s] = cmul(wj, B[j]);
    }
}

// ---------------------------------------------------------------------------
// FUSED double radix-8 (radix-64) Stockham inverse pass (verified R12).
// ---------------------------------------------------------------------------
__global__ __launch_bounds__(256) void fft_stage_r64(
    const float2* __restrict__ in, float2* __restrict__ out, int slog, int M) {
    __shared__ float2 Ysh[32][8][9];
    const int tid = threadIdx.x;
    const int g = tid & 31, u = tid >> 5;
    const int s = 1 << slog;
    const int M8 = M >> 3;
    const int G = blockIdx.x * 32 + g;
    const int q = G & (s - 1);
    const int p0 = G >> slog;

    const int p = p0 + u * M8;
    float2 a[8];
#pragma unroll
    for (int j = 0; j < 8; ++j)
        a[j] = in[q + (size_t)s * (p + j * M)];
    float2 B[8];
    r8core(a, B);
    float si, co;
    __sincosf((0.78539816339744831f / (float)M) * (float)p, &si, &co);  // pi/(4M)*p
    const float2 w = make_float2(co, si);
    Ysh[g][u][0] = B[0];
    float2 wj = w;
    Ysh[g][u][1] = cmul(wj, B[1]);
#pragma unroll
    for (int j = 2; j < 8; ++j) {
        wj = cmul(wj, w);
        Ysh[g][u][j] = cmul(wj, B[j]);
    }
    __syncthreads();

    float2 z[8];
#pragma unroll
    for (int jp = 0; jp < 8; ++jp)
        z[jp] = Ysh[g][jp][u];
    float2 B2[8];
    r8core(z, B2);
    __sincosf((0.78539816339744831f / (float)M8) * (float)p0, &si, &co); // pi/(4*M8)*p0
    const float2 w2 = make_float2(co, si);
    const size_t ob = (size_t)q + (size_t)u * s + (size_t)64 * s * p0;
    out[ob] = B2[0];
    float2 wj2 = w2;
    out[ob + (size_t)8 * s] = cmul(wj2, B2[1]);
#pragma unroll
    for (int j2 = 2; j2 < 8; ++j2) {
        wj2 = cmul(wj2, w2);
        out[ob + (size_t)j2 * 8 * s] = cmul(wj2, B2[j2]);
    }
}

// ---------------------------------------------------------------------------
// Fused unpack + transpose + bf16 cast. x[j] = (j even ? Re : Im) z[j>>1].
// ---------------------------------------------------------------------------
__global__ __launch_bounds__(256) void transpose_wz_bf16(
    const float2* __restrict__ z, ushort* __restrict__ WT,
    int Kd, int Nd, float inv, const float* __restrict__ sc) {
    __shared__ float T[32][33];
    const int n0 = blockIdx.x * 32, k0 = blockIdx.y * 32;
    const int tx = threadIdx.x & 31, ty = threadIdx.x >> 5;
    const float s = inv * sc[0];
    for (int r = ty; r < 32; r += 8) {
        size_t j = (size_t)(k0 + r) * Nd + n0 + tx;
        float2 zz = z[j >> 1];
        T[r][tx] = (j & 1) ? zz.y : zz.x;
    }
    __syncthreads();
    for (int r = ty; r < 32; r += 8)
        WT[(size_t)(n0 + r) * Kd + k0 + tx] = f2bf(T[tx][r] * s);
}

// ---------------------------------------------------------------------------
// x (fp32) -> bf16
// ---------------------------------------------------------------------------
__global__ void x_to_bf16(const float* __restrict__ x, ushort* __restrict__ xb, int n4) {
    int i = blockIdx.x * blockDim.x + threadIdx.x;
    if (i >= n4) return;
    float4 v = *(const float4*)(x + (size_t)i * 4);
    ushort4 o;
    o.x = f2bf(v.x); o.y = f2bf(v.y); o.z = f2bf(v.z); o.w = f2bf(v.w);
    *(ushort4*)(xb + (size_t)i * 4) = o;
}

// ---------------------------------------------------------------------------
// bf16 MFMA GEMM (R11): global_load_lds width=16 staging + XOR swizzle.
// ---------------------------------------------------------------------------
template <int OUTMODE>
__global__ __launch_bounds__(256) void gemm_bt_mfma(
    const ushort* __restrict__ A, const ushort* __restrict__ Bt,
    const float* __restrict__ bias, void* __restrict__ Cout,
    ushort* __restrict__ Vt, int M, int N, int K) {
    __shared__ ushort As[128 * 32];
    __shared__ ushort Bs[128 * 32];
    const int tid = threadIdx.x;
    const int wid = tid >> 6, lane = tid & 63, quad = lane >> 4, l16 = lane & 15;
    const int row0 = blockIdx.y * 128, col0 = blockIdx.x * 128;
    const int mh = (wid >> 1) * 64, nh = (wid & 1) * 64;
    const int swz = (quad ^ (l16 & 3)) * 8;

    f32x4 acc[4][4] = {};

    for (int k0 = 0; k0 < K; k0 += 32) {
        __syncthreads();
#pragma unroll
        for (int rep = 0; rep < 2; ++rep) {
            int c = tid + rep * 256;
            int r = c >> 2;
            int kc = (c & 3) ^ (r & 3);
            ushort* lbA = &As[(rep * 256 + wid * 64) * 8];
            ushort* lbB = &Bs[(rep * 256 + wid * 64) * 8];
            __builtin_amdgcn_global_load_lds(
                AS1U(A + (size_t)(row0 + r) * K + k0 + kc * 8), AS3U(lbA), 16, 0, 0);
            __builtin_amdgcn_global_load_lds(
                AS1U(Bt + (size_t)(col0 + r) * K + k0 + kc * 8), AS3U(lbB), 16, 0, 0);
        }
        __syncthreads();
        s16x8 af[4], bfr[4];
#pragma unroll
        for (int mi = 0; mi < 4; ++mi)
            af[mi] = *(const s16x8*)&As[(mh + mi * 16 + l16) * 32 + swz];
#pragma unroll
        for (int ni = 0; ni < 4; ++ni)
            bfr[ni] = *(const s16x8*)&Bs[(nh + ni * 16 + l16) * 32 + swz];
#pragma unroll
        for (int mi = 0; mi < 4; ++mi)
#pragma unroll
            for (int ni = 0; ni < 4; ++ni)
                acc[mi][ni] = __builtin_amdgcn_mfma_f32_16x16x32_bf16(
                    af[mi], bfr[ni], acc[mi][ni], 0, 0, 0);
    }

#pragma unroll
    for (int mi = 0; mi < 4; ++mi)
#pragma unroll
        for (int ni = 0; ni < 4; ++ni) {
            const int col = col0 + nh + ni * 16 + l16;
            const int rbase = row0 + mh + mi * 16 + quad * 4;
            const float bv = bias[col];
            if (OUTMODE == 0) {
                float* C = (float*)Cout;
#pragma unroll
                for (int j = 0; j < 4; ++j)
                    C[(size_t)(rbase + j) * N + col] = acc[mi][ni][j] + bv;
            } else {
                if (col < 2048) {
                    ushort* C = (ushort*)Cout;
#pragma unroll
                    for (int j = 0; j < 4; ++j)
                        C[(size_t)(rbase + j) * N + col] = f2bf(acc[mi][ni][j] + bv);
                } else {
                    const int bb = rbase >> 11;
                    const int seq = rbase & 2047;
                    const int d = col - 2048;
                    ushort4 pk;
                    pk.x = f2bf(acc[mi][ni][0] + bv);
                    pk.y = f2bf(acc[mi][ni][1] + bv);
                    pk.z = f2bf(acc[mi][ni][2] + bv);
                    pk.w = f2bf(acc[mi][ni][3] + bv);
                    *(ushort4*)&Vt[(size_t)bb * 2097152 + (size_t)d * 2048 + seq] = pk;
                }
            }
        }
}

// ---------------------------------------------------------------------------
// MFMA flash attention, SPLIT-K v3 = R13 kernel (proven no-spill shape:
// 128 q-rows, Qs in LDS, 108 VGPR) with LDS padding replaced by the XOR
// chunk swizzle proven in gemm_bt_mfma: rows are 64 ushorts (128 B);
// logical 16B chunk j of row r lives at slot j^(r&7). All fragment reads
// here have row&7 == l16&7 -> 2-way bank aliasing (free, m136).
// LDS 55296 -> 49152 B => 3 blocks/CU; grid 1024 => 12 waves/CU (was 8).
// Spill-pathology model (R5/6/10/14): LDS small enough for >=4 blocks/CU
// makes the backend clamp VGPRs below the live set -> scratch. At 3
// blocks/CU the implied budget (~170) exceeds need (~108) -> safe.
// Revert triggers: VGPR ~80 or WRITE_SIZE >> 20 MB.
// ---------------------------------------------------------------------------
__global__ __launch_bounds__(256) void attn_fwd_mfma(
    const ushort* __restrict__ qkv, const ushort* __restrict__ Vt,
    ushort* __restrict__ Op, float* __restrict__ Lp) {
    const int bx = blockIdx.x;
    const int qb = bx >> 1, split = bx & 1;
    const int h = blockIdx.y, b = blockIdx.z;
    const int tid = threadIdx.x;
    const int wid = tid >> 6, lane = tid & 63, quad = lane >> 4, l16 = lane & 15;
    const int wq = wid * 32;
    const int kt0 = split * 16;
    const int r7 = l16 & 7;                    // row&7 for all fragment reads
    const float CEXP = 0.18033688011112042f;   // 0.125 * log2(e)

    __shared__ ushort Qs[128 * 64];
    __shared__ ushort Ks[64 * 64];    // [kpos][d], swizzled chunks
    __shared__ ushort Vts[64 * 64];   // [d][kpos], swizzled chunks
    __shared__ ushort Ps[128 * 64];   // [qrow][kpos], swizzled chunks

    // stage Q tile: 128 rows x 64 dims; chunk (c&7) -> slot (c&7)^(r&7)
#pragma unroll
    for (int rep = 0; rep < 4; ++rep) {
        int c = tid + rep * 256;
        int r = c >> 3;
        uint4 v = *(const uint4*)(qkv + (size_t)(b * 2048 + qb * 128 + r) * 3072 + h * 64 + (c & 7) * 8);
        *(uint4*)&Qs[r * 64 + (((c & 7) ^ (r & 7))) * 8] = v;
    }

    uint4 kreg[2], vreg[2];
#pragma unroll
    for (int rep = 0; rep < 2; ++rep) {
        int c = tid + rep * 256;
        int r = c >> 3, co = (c & 7) * 8;
        kreg[rep] = *(const uint4*)(qkv + (size_t)(b * 2048 + kt0 * 64 + r) * 3072 + 1024 + h * 64 + co);
        vreg[rep] = *(const uint4*)(Vt + (size_t)b * 2097152 + (size_t)(h * 64 + r) * 2048 + kt0 * 64 + co);
    }

    f32x4 o[4][2] = {};
    float l_r[2] = {0.f, 0.f};

    for (int tt = 0; tt < 16; ++tt) {
        __syncthreads();
#pragma unroll
        for (int rep = 0; rep < 2; ++rep) {
            int c = tid + rep * 256;
            int r = c >> 3;
            int slot = ((c & 7) ^ (r & 7)) * 8;
            *(uint4*)&Ks[r * 64 + slot] = kreg[rep];
            *(uint4*)&Vts[r * 64 + slot] = vreg[rep];
        }
        if (tt < 15) {
            const int nt = kt0 + tt + 1;
#pragma unroll
            for (int rep = 0; rep < 2; ++rep) {
                int c = tid + rep * 256;
                int r = c >> 3, co = (c & 7) * 8;
                kreg[rep] = *(const uint4*)(qkv + (size_t)(b * 2048 + nt * 64 + r) * 3072 + 1024 + h * 64 + co);
                vreg[rep] = *(const uint4*)(Vt + (size_t)b * 2097152 + (size_t)(h * 64 + r) * 2048 + nt * 64 + co);
            }
        }
        __syncthreads();

        f32x4 s[4][2] = {};
#pragma unroll
        for (int ks = 0; ks < 2; ++ks) {
            const int slot = ((ks * 4 + quad) ^ r7) * 8;
            s16x8 ka[4], qb_[2];
#pragma unroll
            for (int mi = 0; mi < 4; ++mi)
                ka[mi] = *(const s16x8*)&Ks[(mi * 16 + l16) * 64 + slot];
#pragma unroll
            for (int ni = 0; ni < 2; ++ni)
                qb_[ni] = *(const s16x8*)&Qs[(wq + ni * 16 + l16) * 64 + slot];
#pragma unroll
            for (int mi = 0; mi < 4; ++mi)
#pragma unroll
                for (int ni = 0; ni < 2; ++ni)
                    s[mi][ni] = __builtin_amdgcn_mfma_f32_16x16x32_bf16(
                        ka[mi], qb_[ni], s[mi][ni], 0, 0, 0);
        }

        // P write: logical kpos chunk jq = 2*mi + (quad>>1), sub-offset (quad&1)*4
#pragma unroll
        for (int ni = 0; ni < 2; ++ni)
#pragma unroll
            for (int mi = 0; mi < 4; ++mi) {
                ushort4 pk;
#pragma unroll
                for (int j = 0; j < 4; ++j) {
                    float p = exp2f(s[mi][ni][j] * CEXP);
                    l_r[ni] += p;
                    ((ushort*)&pk)[j] = f2bf(p);
                }
                const int jq = 2 * mi + (quad >> 1);
                *(ushort4*)&Ps[(wq + ni * 16 + l16) * 64 + ((jq ^ r7)) * 8 + (quad & 1) * 4] = pk;
            }

#pragma unroll
        for (int ks = 0; ks < 2; ++ks) {
            const int slot = ((ks * 4 + quad) ^ r7) * 8;
            s16x8 va[4], pb[2];
#pragma unroll
            for (int md = 0; md < 4; ++md)
                va[md] = *(const s16x8*)&Vts[(md * 16 + l16) * 64 + slot];
#pragma unroll
            for (int ni = 0; ni < 2; ++ni)
                pb[ni] = *(const s16x8*)&Ps[(wq + ni * 16 + l16) * 64 + slot];
#pragma unroll
            for (int md = 0; md < 4; ++md)
#pragma unroll
                for (int ni = 0; ni < 2; ++ni)
                    o[md][ni] = __builtin_amdgcn_mfma_f32_16x16x32_bf16(
                        va[md], pb[ni], o[md][ni], 0, 0, 0);
        }
    }

    // epilogue: write UNNORMALIZED partials.
#pragma unroll
    for (int ni = 0; ni < 2; ++ni) {
        float l = l_r[ni];
        l += __shfl_xor(l, 16);
        l += __shfl_xor(l, 32);
        const size_t row = (size_t)(b * 2048 + qb * 128 + wq + ni * 16 + l16);
        if (quad == 0)
            Lp[(size_t)split * 65536 + row * 16 + h] = l;
#pragma unroll
        for (int md = 0; md < 4; ++md) {
            ushort4 pk;
#pragma unroll
            for (int j = 0; j < 4; ++j)
                ((ushort*)&pk)[j] = f2bf(o[md][ni][j]);
            *(ushort4*)&Op[(size_t)split * 4194304 + row * 1024 + h * 64 + md * 16 + quad * 4] = pk;
        }
    }
}

// ---------------------------------------------------------------------------
// Combine the two split-K partials: ctx = (O0 + O1) / (l0 + l1).
// ---------------------------------------------------------------------------
__global__ __launch_bounds__(256) void attn_reduce(
    const ushort* __restrict__ Op, const float* __restrict__ Lp,
    ushort* __restrict__ ctx) {
    const int i = blockIdx.x * 256 + threadIdx.x;
    const size_t base = (size_t)i * 4;
    const int row = (int)(base >> 10);
    const int hh = (int)((base & 1023) >> 6);
    const float l = Lp[row * 16 + hh] + Lp[65536 + row * 16 + hh];
    const float inv = 1.f / l;
    ushort4 a = *(const ushort4*)&Op[base];
    ushort4 b = *(const ushort4*)&Op[4194304 + base];
    ushort4 o;
    o.x = f2bf((bf2f(a.x) + bf2f(b.x)) * inv);
    o.y = f2bf((bf2f(a.y) + bf2f(b.y)) * inv);
    o.z = f2bf((bf2f(a.z) + bf2f(b.z)) * inv);
    o.w = f2bf((bf2f(a.w) + bf2f(b.w)) * inv);
    *(ushort4*)&ctx[base] = o;
}

// ---------------------------------------------------------------------------
// Workspace layout (MB offsets), total 78 MB:
//   [0,16M)   A0  } reused: qkv bf16 [0,24M), Vt [24M,32M), ctx [32M,40M)
//   [16M,32M) A1  }
//   [32M,49M) H_a } dead after FFT -> Op [40M,56M), Lp [56M,57M)
//   [49M,54M) H_p
//   [54M,58M) P0   [58M,62M) P1
//   [62M,68M) WaT  [68M,70M) WpT  [70M,78M) x_bf
// ---------------------------------------------------------------------------
extern "C" void kernel_launch(void* const* d_in, const int* in_sizes, int n_in,
                              void* d_out, int out_size, void* d_ws, size_t ws_size,
                              hipStream_t stream) {
    const float* x        = (const float*)d_in[0];
    const float* attn_re  = (const float*)d_in[1];
    const float* attn_im  = (const float*)d_in[2];
    const int*   attn_idx = (const int*)d_in[3];
    const float* attn_sc  = (const float*)d_in[4];
    const float* proj_re  = (const float*)d_in[5];
    const float* proj_im  = (const float*)d_in[6];
    const int*   proj_idx = (const int*)d_in[7];
    const float* proj_sc  = (const float*)d_in[8];
    const float* attn_b   = (const float*)d_in[9];
    const float* proj_b   = (const float*)d_in[10];
    float* out = (float*)d_out;

    const size_t MB = 1048576;
    char* w = (char*)d_ws;
    float2* A0  = (float2*)(w);
    float2* A1  = (float2*)(w + 16 * MB);
    float2* Ha  = (float2*)(w + 32 * MB);
    float2* Hp  = (float2*)(w + 49 * MB);
    float2* P0  = (float2*)(w + 54 * MB);
    float2* P1  = (float2*)(w + 58 * MB);
    ushort* WaT = (ushort*)(w + 62 * MB);
    ushort* WpT = (ushort*)(w + 68 * MB);
    ushort* x_bf= (ushort*)(w + 70 * MB);
    ushort* qkvb= (ushort*)(w);
    ushort* Vt  = (ushort*)(w + 24 * MB);
    ushort* ctx = (ushort*)(w + 32 * MB);
    ushort* Op  = (ushort*)(w + 40 * MB);   // 2 x 8MB bf16 partial O
    float*  Lp  = (float*)(w + 56 * MB);    // 2 x 256KB fp32 partial l

    x_to_bf16<<<4096, 256, 0, stream>>>(x, x_bf, 1048576);

    // one memset covers Ha [32M,~48.8M) and Hp [49M,~53.2M) (gap is dead)
    hipMemsetAsync(w + 32 * MB, 0, 22 * MB, stream);
    scatter_half2<<<(ATTN_KEEP_C + PROJ_KEEP_C) / 256, 256, 0, stream>>>(
        attn_re, attn_im, attn_idx, Ha, proj_re, proj_im, proj_idx, Hp);

    // ---- attn iFFT: pack -> A0; 3 fused radix-64 passes + 1 radix-8 ----
    pack_z<<<ATTN_NC / 256, 256, 0, stream>>>(Ha, A0, ATTN_NC, (float)(2.0 * M_PI / ATTN_PAD_C));
    fft_stage_r64<<<(ATTN_NC / 8) / 256, 256, 0, stream>>>(A0, A1, 0,  ATTN_NC >> 3);
    fft_stage_r64<<<(ATTN_NC / 8) / 256, 256, 0, stream>>>(A1, A0, 6,  ATTN_NC >> 9);
    fft_stage_r64<<<(ATTN_NC / 8) / 256, 256, 0, stream>>>(A0, A1, 12, ATTN_NC >> 15);
    fft_stage_r8 <<<(ATTN_NC / 8) / 256, 256, 0, stream>>>(A1, A0, 18, 1,
        (float)(M_PI / 4.0), ATTN_NC / 8);
    transpose_wz_bf16<<<dim3(3072 / 32, 1024 / 32), 256, 0, stream>>>(
        A0, WaT, 1024, 3072, 1.f / ATTN_PAD_C, attn_sc);

    // ---- proj iFFT: pack -> P0; r2 + 3 fused radix-64 passes ----
    pack_z<<<PROJ_NC / 256, 256, 0, stream>>>(Hp, P0, PROJ_NC, (float)(2.0 * M_PI / PROJ_PAD_C));
    fft_stage<<<(PROJ_NC / 2) / 256, 256, 0, stream>>>(P0, P1, 0, PROJ_NC / 2, PROJ_NC / 2);
    fft_stage_r64<<<(PROJ_NC / 8) / 256, 256, 0, stream>>>(P1, P0, 1,  PROJ_NC >> 4);
    fft_stage_r64<<<(PROJ_NC / 8) / 256, 256, 0, stream>>>(P0, P1, 7,  PROJ_NC >> 10);
    fft_stage_r64<<<(PROJ_NC / 8) / 256, 256, 0, stream>>>(P1, P0, 13, PROJ_NC >> 16);
    transpose_wz_bf16<<<dim3(1024 / 32, 1024 / 32), 256, 0, stream>>>(
        P0, WpT, 1024, 1024, 1.f / PROJ_PAD_C, proj_sc);

    // qkv = x @ Wa + bias (bf16 out; V third written transposed into Vt)
    gemm_bt_mfma<1><<<dim3(3072 / 128, 4096 / 128), 256, 0, stream>>>(
        x_bf, WaT, attn_b, qkvb, Vt, 4096, 3072, 1024);

    // attention: split-K over 2 blocks (3 blocks/CU resident now), reduce
    attn_fwd_mfma<<<dim3(SEQ_C / 64, N_HEADC, BATCH_C), 256, 0, stream>>>(qkvb, Vt, Op, Lp);
    attn_reduce<<<4096, 256, 0, stream>>>(Op, Lp, ctx);

    gemm_bt_mfma<0><<<dim3(1024 / 128, 4096 / 128), 256, 0, stream>>>(
        ctx, WpT, proj_b, out, (ushort*)nullptr, 4096, 1024, 1024);
}

// Round 16
// 341.832 us; speedup vs baseline: 1.1066x; 1.0731x over previous
//
#include <hip/hip_runtime.h>
#include <math.h>

#define N_HEADC  16
#define D_MODELC 1024
#define ATTN_N_C    3145728
#define ATTN_PAD_C  4194304
#define ATTN_NC     2097152   // half-size complex FFT length (2^21 = 8^7)
#define ATTN_KEEP_C 524288
#define PROJ_N_C    1048576
#define PROJ_PAD_C  1048576
#define PROJ_NC     524288    // 2^19 = 2 * 8^6
#define PROJ_KEEP_C 131072
#define BATCH_C 2
#define SEQ_C   2048

typedef __attribute__((ext_vector_type(8))) short s16x8;
typedef __attribute__((ext_vector_type(4))) float f32x4;

#define AS1U(p) ((const __attribute__((address_space(1))) uint*)(p))
#define AS3U(p) ((__attribute__((address_space(3))) uint*)(p))

static __device__ __forceinline__ ushort f2bf(float f) {
    __bf16 b = (__bf16)f;
    return __builtin_bit_cast(ushort, b);
}
static __device__ __forceinline__ float bf2f(ushort u) {
    return __builtin_bit_cast(float, ((uint)u) << 16);
}
static __device__ __forceinline__ float2 cmul(float2 a, float2 b) {
    return make_float2(a.x * b.x - a.y * b.y, a.x * b.y + a.y * b.x);
}
static __device__ __forceinline__ float2 cadd(float2 a, float2 b) {
    return make_float2(a.x + b.x, a.y + b.y);
}
static __device__ __forceinline__ float2 csub(float2 a, float2 b) {
    return make_float2(a.x - b.x, a.y - b.y);
}
static __device__ __forceinline__ float2 crot(float2 z) {   // i*z
    return make_float2(-z.y, z.x);
}

// 8-point inverse DFT core (verified R9). a[0..7] -> B[0..7] (pre-twiddle).
static __device__ __forceinline__ void r8core(const float2* a, float2* B) {
    const float2 t0 = cadd(a[0], a[4]), t1 = csub(a[0], a[4]);
    const float2 t2 = cadd(a[2], a[6]), t3 = csub(a[2], a[6]);
    const float2 t4 = cadd(a[1], a[5]), t5 = csub(a[1], a[5]);
    const float2 t6 = cadd(a[3], a[7]), t7 = csub(a[3], a[7]);
    const float2 E0 = cadd(t0, t2), E2 = csub(t0, t2);
    const float2 E1 = cadd(t1, crot(t3)), E3 = csub(t1, crot(t3));
    const float2 F0 = cadd(t4, t6), F2 = csub(t4, t6);
    const float2 F1 = cadd(t5, crot(t7)), F3 = csub(t5, crot(t7));
    const float c = 0.70710678118654752f;
    const float2 G1 = make_float2(c * (F1.x - F1.y), c * (F1.x + F1.y));   // c(1+i)F1
    const float2 G2 = crot(F2);                                            // iF2
    const float2 G3 = make_float2(c * (-F3.x - F3.y), c * (F3.x - F3.y));  // c(-1+i)F3
    B[0] = cadd(E0, F0); B[4] = csub(E0, F0);
    B[1] = cadd(E1, G1); B[5] = csub(E1, G1);
    B[2] = cadd(E2, G2); B[6] = csub(E2, G2);
    B[3] = cadd(E3, G3); B[7] = csub(E3, G3);
}

// ---------------------------------------------------------------------------
// Combined scatter for both half-spectra (one launch).
// ---------------------------------------------------------------------------
__global__ void scatter_half2(
    const float* __restrict__ re_a, const float* __restrict__ im_a,
    const int* __restrict__ idx_a, float2* __restrict__ Ha,
    const float* __restrict__ re_p, const float* __restrict__ im_p,
    const int* __restrict__ idx_p, float2* __restrict__ Hp) {
    int t = blockIdx.x * blockDim.x + threadIdx.x;
    if (t < ATTN_KEEP_C) {
        Ha[idx_a[t]] = make_float2(re_a[t], im_a[t]);
    } else {
        int u = t - ATTN_KEEP_C;
        Hp[idx_p[u]] = make_float2(re_p[u], im_p[u]);
    }
}

// ---------------------------------------------------------------------------
// Pack half-spectrum H (len Nc+1) into Z (len Nc) for half-size complex iFFT.
// ---------------------------------------------------------------------------
__global__ void pack_z(const float2* __restrict__ H, float2* __restrict__ Z,
                       int Nc, float th0) {
    int k = blockIdx.x * blockDim.x + threadIdx.x;
    if (k >= Nc) return;
    float2 g = H[k];
    float2 hm = H[Nc - k];
    if (k == 0) { g.y = 0.f; hm.y = 0.f; }
    float2 gh = make_float2(hm.x, -hm.y);
    float2 sum = make_float2(g.x + gh.x, g.y + gh.y);
    float2 dif = make_float2(g.x - gh.x, g.y - gh.y);
    float si, co;
    __sincosf(th0 * (float)k, &si, &co);
    float2 t = make_float2(dif.x * co - dif.y * si, dif.x * si + dif.y * co);
    Z[k] = make_float2(sum.x - t.y, sum.y + t.x);
}

// ---------------------------------------------------------------------------
// Radix-2 Stockham inverse stage (proj only: peels 2^19 -> 8^6).
// ---------------------------------------------------------------------------
__global__ void fft_stage(const float2* __restrict__ in, float2* __restrict__ out,
                          int slog, int m, int half) {
    int t = blockIdx.x * blockDim.x + threadIdx.x;
    if (t >= half) return;
    int s = 1 << slog;
    int q = t & (s - 1);
    int p = t >> slog;
    float si, co;
    __sincosf((float)(M_PI / (double)m) * (float)p, &si, &co);
    float2 a = in[q + s * p];
    float2 b = in[q + s * (p + m)];
    float2 su = cadd(a, b);
    float2 di = csub(a, b);
    int ob = q + ((s << 1) * p);
    out[ob]     = su;
    out[ob + s] = make_float2(di.x * co - di.y * si, di.x * si + di.y * co);
}

// ---------------------------------------------------------------------------
// Radix-8 Stockham inverse stage (verified R9) — odd final pass.
// ---------------------------------------------------------------------------
__global__ void fft_stage_r8(const float2* __restrict__ in, float2* __restrict__ out,
                             int slog, int M, float ang0, int eighth) {
    int t = blockIdx.x * blockDim.x + threadIdx.x;
    if (t >= eighth) return;
    const int s = 1 << slog;
    const int q = t & (s - 1);
    const int p = t >> slog;
    float2 a[8];
#pragma unroll
    for (int j = 0; j < 8; ++j)
        a[j] = in[q + (size_t)s * (p + j * M)];
    float2 B[8];
    r8core(a, B);
    float si, co;
    __sincosf(ang0 * (float)p, &si, &co);
    const float2 w = make_float2(co, si);
    const int ob = q + 8 * s * p;
    out[ob] = B[0];
    float2 wj = w;
    out[ob + s] = cmul(wj, B[1]);
#pragma unroll
    for (int j = 2; j < 8; ++j) {
        wj = cmul(wj, w);
        out[ob + j * s] = cmul(wj, B[j]);
    }
}

// ---------------------------------------------------------------------------
// FUSED double radix-8 (radix-64) Stockham inverse pass (verified R12).
// ---------------------------------------------------------------------------
__global__ __launch_bounds__(256) void fft_stage_r64(
    const float2* __restrict__ in, float2* __restrict__ out, int slog, int M) {
    __shared__ float2 Ysh[32][8][9];
    const int tid = threadIdx.x;
    const int g = tid & 31, u = tid >> 5;
    const int s = 1 << slog;
    const int M8 = M >> 3;
    const int G = blockIdx.x * 32 + g;
    const int q = G & (s - 1);
    const int p0 = G >> slog;

    const int p = p0 + u * M8;
    float2 a[8];
#pragma unroll
    for (int j = 0; j < 8; ++j)
        a[j] = in[q + (size_t)s * (p + j * M)];
    float2 B[8];
    r8core(a, B);
    float si, co;
    __sincosf((0.78539816339744831f / (float)M) * (float)p, &si, &co);  // pi/(4M)*p
    const float2 w = make_float2(co, si);
    Ysh[g][u][0] = B[0];
    float2 wj = w;
    Ysh[g][u][1] = cmul(wj, B[1]);
#pragma unroll
    for (int j = 2; j < 8; ++j) {
        wj = cmul(wj, w);
        Ysh[g][u][j] = cmul(wj, B[j]);
    }
    __syncthreads();

    float2 z[8];
#pragma unroll
    for (int jp = 0; jp < 8; ++jp)
        z[jp] = Ysh[g][jp][u];
    float2 B2[8];
    r8core(z, B2);
    __sincosf((0.78539816339744831f / (float)M8) * (float)p0, &si, &co); // pi/(4*M8)*p0
    const float2 w2 = make_float2(co, si);
    const size_t ob = (size_t)q + (size_t)u * s + (size_t)64 * s * p0;
    out[ob] = B2[0];
    float2 wj2 = w2;
    out[ob + (size_t)8 * s] = cmul(wj2, B2[1]);
#pragma unroll
    for (int j2 = 2; j2 < 8; ++j2) {
        wj2 = cmul(wj2, w2);
        out[ob + (size_t)j2 * 8 * s] = cmul(wj2, B2[j2]);
    }
}

// ---------------------------------------------------------------------------
// Fused unpack + transpose + bf16 cast. x[j] = (j even ? Re : Im) z[j>>1].
// ---------------------------------------------------------------------------
__global__ __launch_bounds__(256) void transpose_wz_bf16(
    const float2* __restrict__ z, ushort* __restrict__ WT,
    int Kd, int Nd, float inv, const float* __restrict__ sc) {
    __shared__ float T[32][33];
    const int n0 = blockIdx.x * 32, k0 = blockIdx.y * 32;
    const int tx = threadIdx.x & 31, ty = threadIdx.x >> 5;
    const float s = inv * sc[0];
    for (int r = ty; r < 32; r += 8) {
        size_t j = (size_t)(k0 + r) * Nd + n0 + tx;
        float2 zz = z[j >> 1];
        T[r][tx] = (j & 1) ? zz.y : zz.x;
    }
    __syncthreads();
    for (int r = ty; r < 32; r += 8)
        WT[(size_t)(n0 + r) * Kd + k0 + tx] = f2bf(T[tx][r] * s);
}

// ---------------------------------------------------------------------------
// x (fp32) -> bf16
// ---------------------------------------------------------------------------
__global__ void x_to_bf16(const float* __restrict__ x, ushort* __restrict__ xb, int n4) {
    int i = blockIdx.x * blockDim.x + threadIdx.x;
    if (i >= n4) return;
    float4 v = *(const float4*)(x + (size_t)i * 4);
    ushort4 o;
    o.x = f2bf(v.x); o.y = f2bf(v.y); o.z = f2bf(v.z); o.w = f2bf(v.w);
    *(ushort4*)(xb + (size_t)i * 4) = o;
}

// ---------------------------------------------------------------------------
// bf16 MFMA GEMM (R11): global_load_lds width=16 staging + XOR swizzle.
// ---------------------------------------------------------------------------
template <int OUTMODE>
__global__ __launch_bounds__(256) void gemm_bt_mfma(
    const ushort* __restrict__ A, const ushort* __restrict__ Bt,
    const float* __restrict__ bias, void* __restrict__ Cout,
    ushort* __restrict__ Vt, int M, int N, int K) {
    __shared__ ushort As[128 * 32];
    __shared__ ushort Bs[128 * 32];
    const int tid = threadIdx.x;
    const int wid = tid >> 6, lane = tid & 63, quad = lane >> 4, l16 = lane & 15;
    const int row0 = blockIdx.y * 128, col0 = blockIdx.x * 128;
    const int mh = (wid >> 1) * 64, nh = (wid & 1) * 64;
    const int swz = (quad ^ (l16 & 3)) * 8;

    f32x4 acc[4][4] = {};

    for (int k0 = 0; k0 < K; k0 += 32) {
        __syncthreads();
#pragma unroll
        for (int rep = 0; rep < 2; ++rep) {
            int c = tid + rep * 256;
            int r = c >> 2;
            int kc = (c & 3) ^ (r & 3);
            ushort* lbA = &As[(rep * 256 + wid * 64) * 8];
            ushort* lbB = &Bs[(rep * 256 + wid * 64) * 8];
            __builtin_amdgcn_global_load_lds(
                AS1U(A + (size_t)(row0 + r) * K + k0 + kc * 8), AS3U(lbA), 16, 0, 0);
            __builtin_amdgcn_global_load_lds(
                AS1U(Bt + (size_t)(col0 + r) * K + k0 + kc * 8), AS3U(lbB), 16, 0, 0);
        }
        __syncthreads();
        s16x8 af[4], bfr[4];
#pragma unroll
        for (int mi = 0; mi < 4; ++mi)
            af[mi] = *(const s16x8*)&As[(mh + mi * 16 + l16) * 32 + swz];
#pragma unroll
        for (int ni = 0; ni < 4; ++ni)
            bfr[ni] = *(const s16x8*)&Bs[(nh + ni * 16 + l16) * 32 + swz];
#pragma unroll
        for (int mi = 0; mi < 4; ++mi)
#pragma unroll
            for (int ni = 0; ni < 4; ++ni)
                acc[mi][ni] = __builtin_amdgcn_mfma_f32_16x16x32_bf16(
                    af[mi], bfr[ni], acc[mi][ni], 0, 0, 0);
    }

#pragma unroll
    for (int mi = 0; mi < 4; ++mi)
#pragma unroll
        for (int ni = 0; ni < 4; ++ni) {
            const int col = col0 + nh + ni * 16 + l16;
            const int rbase = row0 + mh + mi * 16 + quad * 4;
            const float bv = bias[col];
            if (OUTMODE == 0) {
                float* C = (float*)Cout;
#pragma unroll
                for (int j = 0; j < 4; ++j)
                    C[(size_t)(rbase + j) * N + col] = acc[mi][ni][j] + bv;
            } else {
                if (col < 2048) {
                    ushort* C = (ushort*)Cout;
#pragma unroll
                    for (int j = 0; j < 4; ++j)
                        C[(size_t)(rbase + j) * N + col] = f2bf(acc[mi][ni][j] + bv);
                } else {
                    const int bb = rbase >> 11;
                    const int seq = rbase & 2047;
                    const int d = col - 2048;
                    ushort4 pk;
                    pk.x = f2bf(acc[mi][ni][0] + bv);
                    pk.y = f2bf(acc[mi][ni][1] + bv);
                    pk.z = f2bf(acc[mi][ni][2] + bv);
                    pk.w = f2bf(acc[mi][ni][3] + bv);
                    *(ushort4*)&Vt[(size_t)bb * 2097152 + (size_t)d * 2048 + seq] = pk;
                }
            }
        }
}

// ---------------------------------------------------------------------------
// MFMA flash attention, SPLIT-K v4 = R15 kernel + __launch_bounds__(256, 2).
// DIAGNOSIS (R5/6/10/14/15): with plain launch_bounds(256) the backend
// erratically targets high waves/EU and clamps VGPR below the ~108 live set
// -> per-iteration scratch spills (WRITE 70-440 MB). (256,2) pins the
// target: min 2 waves/EU => allocator budget 512/2=256 VGPR => no clamp.
// Runtime occupancy = min(LDS 49152 -> 3 blk/CU, VGPR -> 4, grid -> 4) = 3.
// LDS padding replaced by XOR chunk swizzle (slot = chunk^(row&7)); all
// fragment reads have row&7==l16&7 -> 2-way aliasing (free, m136).
// REVERT TRIGGER: if VGPR ~80 / WRITE >> 20MB again -> back to R12, stop.
// ---------------------------------------------------------------------------
__global__ __launch_bounds__(256, 2) void attn_fwd_mfma(
    const ushort* __restrict__ qkv, const ushort* __restrict__ Vt,
    ushort* __restrict__ Op, float* __restrict__ Lp) {
    const int bx = blockIdx.x;
    const int qb = bx >> 1, split = bx & 1;
    const int h = blockIdx.y, b = blockIdx.z;
    const int tid = threadIdx.x;
    const int wid = tid >> 6, lane = tid & 63, quad = lane >> 4, l16 = lane & 15;
    const int wq = wid * 32;
    const int kt0 = split * 16;
    const int r7 = l16 & 7;                    // row&7 for all fragment reads
    const float CEXP = 0.18033688011112042f;   // 0.125 * log2(e)

    __shared__ ushort Qs[128 * 64];
    __shared__ ushort Ks[64 * 64];    // [kpos][d], swizzled chunks
    __shared__ ushort Vts[64 * 64];   // [d][kpos], swizzled chunks
    __shared__ ushort Ps[128 * 64];   // [qrow][kpos], swizzled chunks

    // stage Q tile: 128 rows x 64 dims; chunk (c&7) -> slot (c&7)^(r&7)
#pragma unroll
    for (int rep = 0; rep < 4; ++rep) {
        int c = tid + rep * 256;
        int r = c >> 3;
        uint4 v = *(const uint4*)(qkv + (size_t)(b * 2048 + qb * 128 + r) * 3072 + h * 64 + (c & 7) * 8);
        *(uint4*)&Qs[r * 64 + (((c & 7) ^ (r & 7))) * 8] = v;
    }

    uint4 kreg[2], vreg[2];
#pragma unroll
    for (int rep = 0; rep < 2; ++rep) {
        int c = tid + rep * 256;
        int r = c >> 3, co = (c & 7) * 8;
        kreg[rep] = *(const uint4*)(qkv + (size_t)(b * 2048 + kt0 * 64 + r) * 3072 + 1024 + h * 64 + co);
        vreg[rep] = *(const uint4*)(Vt + (size_t)b * 2097152 + (size_t)(h * 64 + r) * 2048 + kt0 * 64 + co);
    }

    f32x4 o[4][2] = {};
    float l_r[2] = {0.f, 0.f};

    for (int tt = 0; tt < 16; ++tt) {
        __syncthreads();
#pragma unroll
        for (int rep = 0; rep < 2; ++rep) {
            int c = tid + rep * 256;
            int r = c >> 3;
            int slot = ((c & 7) ^ (r & 7)) * 8;
            *(uint4*)&Ks[r * 64 + slot] = kreg[rep];
            *(uint4*)&Vts[r * 64 + slot] = vreg[rep];
        }
        if (tt < 15) {
            const int nt = kt0 + tt + 1;
#pragma unroll
            for (int rep = 0; rep < 2; ++rep) {
                int c = tid + rep * 256;
                int r = c >> 3, co = (c & 7) * 8;
                kreg[rep] = *(const uint4*)(qkv + (size_t)(b * 2048 + nt * 64 + r) * 3072 + 1024 + h * 64 + co);
                vreg[rep] = *(const uint4*)(Vt + (size_t)b * 2097152 + (size_t)(h * 64 + r) * 2048 + nt * 64 + co);
            }
        }
        __syncthreads();

        f32x4 s[4][2] = {};
#pragma unroll
        for (int ks = 0; ks < 2; ++ks) {
            const int slot = ((ks * 4 + quad) ^ r7) * 8;
            s16x8 ka[4], qb_[2];
#pragma unroll
            for (int mi = 0; mi < 4; ++mi)
                ka[mi] = *(const s16x8*)&Ks[(mi * 16 + l16) * 64 + slot];
#pragma unroll
            for (int ni = 0; ni < 2; ++ni)
                qb_[ni] = *(const s16x8*)&Qs[(wq + ni * 16 + l16) * 64 + slot];
#pragma unroll
            for (int mi = 0; mi < 4; ++mi)
#pragma unroll
                for (int ni = 0; ni < 2; ++ni)
                    s[mi][ni] = __builtin_amdgcn_mfma_f32_16x16x32_bf16(
                        ka[mi], qb_[ni], s[mi][ni], 0, 0, 0);
        }

        // P write: logical kpos chunk jq = 2*mi + (quad>>1), sub-offset (quad&1)*4
#pragma unroll
        for (int ni = 0; ni < 2; ++ni)
#pragma unroll
            for (int mi = 0; mi < 4; ++mi) {
                ushort4 pk;
#pragma unroll
                for (int j = 0; j < 4; ++j) {
                    float p = exp2f(s[mi][ni][j] * CEXP);
                    l_r[ni] += p;
                    ((ushort*)&pk)[j] = f2bf(p);
                }
                const int jq = 2 * mi + (quad >> 1);
                *(ushort4*)&Ps[(wq + ni * 16 + l16) * 64 + ((jq ^ r7)) * 8 + (quad & 1) * 4] = pk;
            }

#pragma unroll
        for (int ks = 0; ks < 2; ++ks) {
            const int slot = ((ks * 4 + quad) ^ r7) * 8;
            s16x8 va[4], pb[2];
#pragma unroll
            for (int md = 0; md < 4; ++md)
                va[md] = *(const s16x8*)&Vts[(md * 16 + l16) * 64 + slot];
#pragma unroll
            for (int ni = 0; ni < 2; ++ni)
                pb[ni] = *(const s16x8*)&Ps[(wq + ni * 16 + l16) * 64 + slot];
#pragma unroll
            for (int md = 0; md < 4; ++md)
#pragma unroll
                for (int ni = 0; ni < 2; ++ni)
                    o[md][ni] = __builtin_amdgcn_mfma_f32_16x16x32_bf16(
                        va[md], pb[ni], o[md][ni], 0, 0, 0);
        }
    }

    // epilogue: write UNNORMALIZED partials.
#pragma unroll
    for (int ni = 0; ni < 2; ++ni) {
        float l = l_r[ni];
        l += __shfl_xor(l, 16);
        l += __shfl_xor(l, 32);
        const size_t row = (size_t)(b * 2048 + qb * 128 + wq + ni * 16 + l16);
        if (quad == 0)
            Lp[(size_t)split * 65536 + row * 16 + h] = l;
#pragma unroll
        for (int md = 0; md < 4; ++md) {
            ushort4 pk;
#pragma unroll
            for (int j = 0; j < 4; ++j)
                ((ushort*)&pk)[j] = f2bf(o[md][ni][j]);
            *(ushort4*)&Op[(size_t)split * 4194304 + row * 1024 + h * 64 + md * 16 + quad * 4] = pk;
        }
    }
}

// ---------------------------------------------------------------------------
// Combine the two split-K partials: ctx = (O0 + O1) / (l0 + l1).
// ---------------------------------------------------------------------------
__global__ __launch_bounds__(256) void attn_reduce(
    const ushort* __restrict__ Op, const float* __restrict__ Lp,
    ushort* __restrict__ ctx) {
    const int i = blockIdx.x * 256 + threadIdx.x;
    const size_t base = (size_t)i * 4;
    const int row = (int)(base >> 10);
    const int hh = (int)((base & 1023) >> 6);
    const float l = Lp[row * 16 + hh] + Lp[65536 + row * 16 + hh];
    const float inv = 1.f / l;
    ushort4 a = *(const ushort4*)&Op[base];
    ushort4 b = *(const ushort4*)&Op[4194304 + base];
    ushort4 o;
    o.x = f2bf((bf2f(a.x) + bf2f(b.x)) * inv);
    o.y = f2bf((bf2f(a.y) + bf2f(b.y)) * inv);
    o.z = f2bf((bf2f(a.z) + bf2f(b.z)) * inv);
    o.w = f2bf((bf2f(a.w) + bf2f(b.w)) * inv);
    *(ushort4*)&ctx[base] = o;
}

// ---------------------------------------------------------------------------
// Workspace layout (MB offsets), total 78 MB:
//   [0,16M)   A0  } reused: qkv bf16 [0,24M), Vt [24M,32M), ctx [32M,40M)
//   [16M,32M) A1  }
//   [32M,49M) H_a } dead after FFT -> Op [40M,56M), Lp [56M,57M)
//   [49M,54M) H_p
//   [54M,58M) P0   [58M,62M) P1
//   [62M,68M) WaT  [68M,70M) WpT  [70M,78M) x_bf
// ---------------------------------------------------------------------------
extern "C" void kernel_launch(void* const* d_in, const int* in_sizes, int n_in,
                              void* d_out, int out_size, void* d_ws, size_t ws_size,
                              hipStream_t stream) {
    const float* x        = (const float*)d_in[0];
    const float* attn_re  = (const float*)d_in[1];
    const float* attn_im  = (const float*)d_in[2];
    const int*   attn_idx = (const int*)d_in[3];
    const float* attn_sc  = (const float*)d_in[4];
    const float* proj_re  = (const float*)d_in[5];
    const float* proj_im  = (const float*)d_in[6];
    const int*   proj_idx = (const int*)d_in[7];
    const float* proj_sc  = (const float*)d_in[8];
    const float* attn_b   = (const float*)d_in[9];
    const float* proj_b   = (const float*)d_in[10];
    float* out = (float*)d_out;

    const size_t MB = 1048576;
    char* w = (char*)d_ws;
    float2* A0  = (float2*)(w);
    float2* A1  = (float2*)(w + 16 * MB);
    float2* Ha  = (float2*)(w + 32 * MB);
    float2* Hp  = (float2*)(w + 49 * MB);
    float2* P0  = (float2*)(w + 54 * MB);
    float2* P1  = (float2*)(w + 58 * MB);
    ushort* WaT = (ushort*)(w + 62 * MB);
    ushort* WpT = (ushort*)(w + 68 * MB);
    ushort* x_bf= (ushort*)(w + 70 * MB);
    ushort* qkvb= (ushort*)(w);
    ushort* Vt  = (ushort*)(w + 24 * MB);
    ushort* ctx = (ushort*)(w + 32 * MB);
    ushort* Op  = (ushort*)(w + 40 * MB);   // 2 x 8MB bf16 partial O
    float*  Lp  = (float*)(w + 56 * MB);    // 2 x 256KB fp32 partial l

    x_to_bf16<<<4096, 256, 0, stream>>>(x, x_bf, 1048576);

    // one memset covers Ha [32M,~48.8M) and Hp [49M,~53.2M) (gap is dead)
    hipMemsetAsync(w + 32 * MB, 0, 22 * MB, stream);
    scatter_half2<<<(ATTN_KEEP_C + PROJ_KEEP_C) / 256, 256, 0, stream>>>(
        attn_re, attn_im, attn_idx, Ha, proj_re, proj_im, proj_idx, Hp);

    // ---- attn iFFT: pack -> A0; 3 fused radix-64 passes + 1 radix-8 ----
    pack_z<<<ATTN_NC / 256, 256, 0, stream>>>(Ha, A0, ATTN_NC, (float)(2.0 * M_PI / ATTN_PAD_C));
    fft_stage_r64<<<(ATTN_NC / 8) / 256, 256, 0, stream>>>(A0, A1, 0,  ATTN_NC >> 3);
    fft_stage_r64<<<(ATTN_NC / 8) / 256, 256, 0, stream>>>(A1, A0, 6,  ATTN_NC >> 9);
    fft_stage_r64<<<(ATTN_NC / 8) / 256, 256, 0, stream>>>(A0, A1, 12, ATTN_NC >> 15);
    fft_stage_r8 <<<(ATTN_NC / 8) / 256, 256, 0, stream>>>(A1, A0, 18, 1,
        (float)(M_PI / 4.0), ATTN_NC / 8);
    transpose_wz_bf16<<<dim3(3072 / 32, 1024 / 32), 256, 0, stream>>>(
        A0, WaT, 1024, 3072, 1.f / ATTN_PAD_C, attn_sc);

    // ---- proj iFFT: pack -> P0; r2 + 3 fused radix-64 passes ----
    pack_z<<<PROJ_NC / 256, 256, 0, stream>>>(Hp, P0, PROJ_NC, (float)(2.0 * M_PI / PROJ_PAD_C));
    fft_stage<<<(PROJ_NC / 2) / 256, 256, 0, stream>>>(P0, P1, 0, PROJ_NC / 2, PROJ_NC / 2);
    fft_stage_r64<<<(PROJ_NC / 8) / 256, 256, 0, stream>>>(P1, P0, 1,  PROJ_NC >> 4);
    fft_stage_r64<<<(PROJ_NC / 8) / 256, 256, 0, stream>>>(P0, P1, 7,  PROJ_NC >> 10);
    fft_stage_r64<<<(PROJ_NC / 8) / 256, 256, 0, stream>>>(P1, P0, 13, PROJ_NC >> 16);
    transpose_wz_bf16<<<dim3(1024 / 32, 1024 / 32), 256, 0, stream>>>(
        P0, WpT, 1024, 1024, 1.f / PROJ_PAD_C, proj_sc);

    // qkv = x @ Wa + bias (bf16 out; V third written transposed into Vt)
    gemm_bt_mfma<1><<<dim3(3072 / 128, 4096 / 128), 256, 0, stream>>>(
        x_bf, WaT, attn_b, qkvb, Vt, 4096, 3072, 1024);

    // attention: split-K over 2 blocks (3 blocks/CU with pinned VGPR budget)
    attn_fwd_mfma<<<dim3(SEQ_C / 64, N_HEADC, BATCH_C), 256, 0, stream>>>(qkvb, Vt, Op, Lp);
    attn_reduce<<<4096, 256, 0, stream>>>(Op, Lp, ctx);

    gemm_bt_mfma<0><<<dim3(1024 / 128, 4096 / 128), 256, 0, stream>>>(
        ctx, WpT, proj_b, out, (ushort*)nullptr, 4096, 1024, 1024);
}

// Round 17
// 313.861 us; speedup vs baseline: 1.2052x; 1.0891x over previous
//
#include <hip/hip_runtime.h>
#include <math.h>

#define N_HEADC  16
#define D_MODELC 1024
#define ATTN_N_C    3145728
#define ATTN_PAD_C  4194304
#define ATTN_NC     2097152   // half-size complex FFT length (2^21 = 8^7)
#define ATTN_KEEP_C 524288
#define PROJ_N_C    1048576
#define PROJ_PAD_C  1048576
#define PROJ_NC     524288    // 2^19 = 2 * 8^6
#define PROJ_KEEP_C 131072
#define BATCH_C 2
#define SEQ_C   2048

typedef __attribute__((ext_vector_type(8))) short s16x8;
typedef __attribute__((ext_vector_type(4))) float f32x4;

#define AS1U(p) ((const __attribute__((address_space(1))) uint*)(p))
#define AS3U(p) ((__attribute__((address_space(3))) uint*)(p))

static __device__ __forceinline__ ushort f2bf(float f) {
    __bf16 b = (__bf16)f;
    return __builtin_bit_cast(ushort, b);
}
static __device__ __forceinline__ float bf2f(ushort u) {
    return __builtin_bit_cast(float, ((uint)u) << 16);
}
static __device__ __forceinline__ float2 cmul(float2 a, float2 b) {
    return make_float2(a.x * b.x - a.y * b.y, a.x * b.y + a.y * b.x);
}
static __device__ __forceinline__ float2 cadd(float2 a, float2 b) {
    return make_float2(a.x + b.x, a.y + b.y);
}
static __device__ __forceinline__ float2 csub(float2 a, float2 b) {
    return make_float2(a.x - b.x, a.y - b.y);
}
static __device__ __forceinline__ float2 crot(float2 z) {   // i*z
    return make_float2(-z.y, z.x);
}

// 8-point inverse DFT core (verified R9). a[0..7] -> B[0..7] (pre-twiddle).
static __device__ __forceinline__ void r8core(const float2* a, float2* B) {
    const float2 t0 = cadd(a[0], a[4]), t1 = csub(a[0], a[4]);
    const float2 t2 = cadd(a[2], a[6]), t3 = csub(a[2], a[6]);
    const float2 t4 = cadd(a[1], a[5]), t5 = csub(a[1], a[5]);
    const float2 t6 = cadd(a[3], a[7]), t7 = csub(a[3], a[7]);
    const float2 E0 = cadd(t0, t2), E2 = csub(t0, t2);
    const float2 E1 = cadd(t1, crot(t3)), E3 = csub(t1, crot(t3));
    const float2 F0 = cadd(t4, t6), F2 = csub(t4, t6);
    const float2 F1 = cadd(t5, crot(t7)), F3 = csub(t5, crot(t7));
    const float c = 0.70710678118654752f;
    const float2 G1 = make_float2(c * (F1.x - F1.y), c * (F1.x + F1.y));   // c(1+i)F1
    const float2 G2 = crot(F2);                                            // iF2
    const float2 G3 = make_float2(c * (-F3.x - F3.y), c * (F3.x - F3.y));  // c(-1+i)F3
    B[0] = cadd(E0, F0); B[4] = csub(E0, F0);
    B[1] = cadd(E1, G1); B[5] = csub(E1, G1);
    B[2] = cadd(E2, G2); B[6] = csub(E2, G2);
    B[3] = cadd(E3, G3); B[7] = csub(E3, G3);
}

// ---------------------------------------------------------------------------
// Combined scatter for both half-spectra (one launch).
// ---------------------------------------------------------------------------
__global__ void scatter_half2(
    const float* __restrict__ re_a, const float* __restrict__ im_a,
    const int* __restrict__ idx_a, float2* __restrict__ Ha,
    const float* __restrict__ re_p, const float* __restrict__ im_p,
    const int* __restrict__ idx_p, float2* __restrict__ Hp) {
    int t = blockIdx.x * blockDim.x + threadIdx.x;
    if (t < ATTN_KEEP_C) {
        Ha[idx_a[t]] = make_float2(re_a[t], im_a[t]);
    } else {
        int u = t - ATTN_KEEP_C;
        Hp[idx_p[u]] = make_float2(re_p[u], im_p[u]);
    }
}

// ---------------------------------------------------------------------------
// Pack half-spectrum H (len Nc+1) into Z (len Nc) for half-size complex iFFT.
// ---------------------------------------------------------------------------
__global__ void pack_z(const float2* __restrict__ H, float2* __restrict__ Z,
                       int Nc, float th0) {
    int k = blockIdx.x * blockDim.x + threadIdx.x;
    if (k >= Nc) return;
    float2 g = H[k];
    float2 hm = H[Nc - k];
    if (k == 0) { g.y = 0.f; hm.y = 0.f; }
    float2 gh = make_float2(hm.x, -hm.y);
    float2 sum = make_float2(g.x + gh.x, g.y + gh.y);
    float2 dif = make_float2(g.x - gh.x, g.y - gh.y);
    float si, co;
    __sincosf(th0 * (float)k, &si, &co);
    float2 t = make_float2(dif.x * co - dif.y * si, dif.x * si + dif.y * co);
    Z[k] = make_float2(sum.x - t.y, sum.y + t.x);
}

// ---------------------------------------------------------------------------
// Radix-2 Stockham inverse stage (proj only: peels 2^19 -> 8^6).
// ---------------------------------------------------------------------------
__global__ void fft_stage(const float2* __restrict__ in, float2* __restrict__ out,
                          int slog, int m, int half) {
    int t = blockIdx.x * blockDim.x + threadIdx.x;
    if (t >= half) return;
    int s = 1 << slog;
    int q = t & (s - 1);
    int p = t >> slog;
    float si, co;
    __sincosf((float)(M_PI / (double)m) * (float)p, &si, &co);
    float2 a = in[q + s * p];
    float2 b = in[q + s * (p + m)];
    float2 su = cadd(a, b);
    float2 di = csub(a, b);
    int ob = q + ((s << 1) * p);
    out[ob]     = su;
    out[ob + s] = make_float2(di.x * co - di.y * si, di.x * si + di.y * co);
}

// ---------------------------------------------------------------------------
// Radix-8 Stockham inverse stage (verified R9) — odd final pass.
// ---------------------------------------------------------------------------
__global__ void fft_stage_r8(const float2* __restrict__ in, float2* __restrict__ out,
                             int slog, int M, float ang0, int eighth) {
    int t = blockIdx.x * blockDim.x + threadIdx.x;
    if (t >= eighth) return;
    const int s = 1 << slog;
    const int q = t & (s - 1);
    const int p = t >> slog;
    float2 a[8];
#pragma unroll
    for (int j = 0; j < 8; ++j)
        a[j] = in[q + (size_t)s * (p + j * M)];
    float2 B[8];
    r8core(a, B);
    float si, co;
    __sincosf(ang0 * (float)p, &si, &co);
    const float2 w = make_float2(co, si);
    const int ob = q + 8 * s * p;
    out[ob] = B[0];
    float2 wj = w;
    out[ob + s] = cmul(wj, B[1]);
#pragma unroll
    for (int j = 2; j < 8; ++j) {
        wj = cmul(wj, w);
        out[ob + j * s] = cmul(wj, B[j]);
    }
}

// ---------------------------------------------------------------------------
// FUSED double radix-8 (radix-64) Stockham inverse pass (verified R12).
// ---------------------------------------------------------------------------
__global__ __launch_bounds__(256) void fft_stage_r64(
    const float2* __restrict__ in, float2* __restrict__ out, int slog, int M) {
    __shared__ float2 Ysh[32][8][9];
    const int tid = threadIdx.x;
    const int g = tid & 31, u = tid >> 5;
    const int s = 1 << slog;
    const int M8 = M >> 3;
    const int G = blockIdx.x * 32 + g;
    const int q = G & (s - 1);
    const int p0 = G >> slog;

    const int p = p0 + u * M8;
    float2 a[8];
#pragma unroll
    for (int j = 0; j < 8; ++j)
        a[j] = in[q + (size_t)s * (p + j * M)];
    float2 B[8];
    r8core(a, B);
    float si, co;
    __sincosf((0.78539816339744831f / (float)M) * (float)p, &si, &co);  // pi/(4M)*p
    const float2 w = make_float2(co, si);
    Ysh[g][u][0] = B[0];
    float2 wj = w;
    Ysh[g][u][1] = cmul(wj, B[1]);
#pragma unroll
    for (int j = 2; j < 8; ++j) {
        wj = cmul(wj, w);
        Ysh[g][u][j] = cmul(wj, B[j]);
    }
    __syncthreads();

    float2 z[8];
#pragma unroll
    for (int jp = 0; jp < 8; ++jp)
        z[jp] = Ysh[g][jp][u];
    float2 B2[8];
    r8core(z, B2);
    __sincosf((0.78539816339744831f / (float)M8) * (float)p0, &si, &co); // pi/(4*M8)*p0
    const float2 w2 = make_float2(co, si);
    const size_t ob = (size_t)q + (size_t)u * s + (size_t)64 * s * p0;
    out[ob] = B2[0];
    float2 wj2 = w2;
    out[ob + (size_t)8 * s] = cmul(wj2, B2[1]);
#pragma unroll
    for (int j2 = 2; j2 < 8; ++j2) {
        wj2 = cmul(wj2, w2);
        out[ob + (size_t)j2 * 8 * s] = cmul(wj2, B2[j2]);
    }
}

// ---------------------------------------------------------------------------
// Fused unpack + transpose + bf16 cast. x[j] = (j even ? Re : Im) z[j>>1].
// ---------------------------------------------------------------------------
__global__ __launch_bounds__(256) void transpose_wz_bf16(
    const float2* __restrict__ z, ushort* __restrict__ WT,
    int Kd, int Nd, float inv, const float* __restrict__ sc) {
    __shared__ float T[32][33];
    const int n0 = blockIdx.x * 32, k0 = blockIdx.y * 32;
    const int tx = threadIdx.x & 31, ty = threadIdx.x >> 5;
    const float s = inv * sc[0];
    for (int r = ty; r < 32; r += 8) {
        size_t j = (size_t)(k0 + r) * Nd + n0 + tx;
        float2 zz = z[j >> 1];
        T[r][tx] = (j & 1) ? zz.y : zz.x;
    }
    __syncthreads();
    for (int r = ty; r < 32; r += 8)
        WT[(size_t)(n0 + r) * Kd + k0 + tx] = f2bf(T[tx][r] * s);
}

// ---------------------------------------------------------------------------
// x (fp32) -> bf16
// ---------------------------------------------------------------------------
__global__ void x_to_bf16(const float* __restrict__ x, ushort* __restrict__ xb, int n4) {
    int i = blockIdx.x * blockDim.x + threadIdx.x;
    if (i >= n4) return;
    float4 v = *(const float4*)(x + (size_t)i * 4);
    ushort4 o;
    o.x = f2bf(v.x); o.y = f2bf(v.y); o.z = f2bf(v.z); o.w = f2bf(v.w);
    *(ushort4*)(xb + (size_t)i * 4) = o;
}

// ---------------------------------------------------------------------------
// bf16 MFMA GEMM (R11): global_load_lds width=16 staging + XOR swizzle.
// ---------------------------------------------------------------------------
template <int OUTMODE>
__global__ __launch_bounds__(256) void gemm_bt_mfma(
    const ushort* __restrict__ A, const ushort* __restrict__ Bt,
    const float* __restrict__ bias, void* __restrict__ Cout,
    ushort* __restrict__ Vt, int M, int N, int K) {
    __shared__ ushort As[128 * 32];
    __shared__ ushort Bs[128 * 32];
    const int tid = threadIdx.x;
    const int wid = tid >> 6, lane = tid & 63, quad = lane >> 4, l16 = lane & 15;
    const int row0 = blockIdx.y * 128, col0 = blockIdx.x * 128;
    const int mh = (wid >> 1) * 64, nh = (wid & 1) * 64;
    const int swz = (quad ^ (l16 & 3)) * 8;

    f32x4 acc[4][4] = {};

    for (int k0 = 0; k0 < K; k0 += 32) {
        __syncthreads();
#pragma unroll
        for (int rep = 0; rep < 2; ++rep) {
            int c = tid + rep * 256;
            int r = c >> 2;
            int kc = (c & 3) ^ (r & 3);
            ushort* lbA = &As[(rep * 256 + wid * 64) * 8];
            ushort* lbB = &Bs[(rep * 256 + wid * 64) * 8];
            __builtin_amdgcn_global_load_lds(
                AS1U(A + (size_t)(row0 + r) * K + k0 + kc * 8), AS3U(lbA), 16, 0, 0);
            __builtin_amdgcn_global_load_lds(
                AS1U(Bt + (size_t)(col0 + r) * K + k0 + kc * 8), AS3U(lbB), 16, 0, 0);
        }
        __syncthreads();
        s16x8 af[4], bfr[4];
#pragma unroll
        for (int mi = 0; mi < 4; ++mi)
            af[mi] = *(const s16x8*)&As[(mh + mi * 16 + l16) * 32 + swz];
#pragma unroll
        for (int ni = 0; ni < 4; ++ni)
            bfr[ni] = *(const s16x8*)&Bs[(nh + ni * 16 + l16) * 32 + swz];
#pragma unroll
        for (int mi = 0; mi < 4; ++mi)
#pragma unroll
            for (int ni = 0; ni < 4; ++ni)
                acc[mi][ni] = __builtin_amdgcn_mfma_f32_16x16x32_bf16(
                    af[mi], bfr[ni], acc[mi][ni], 0, 0, 0);
    }

#pragma unroll
    for (int mi = 0; mi < 4; ++mi)
#pragma unroll
        for (int ni = 0; ni < 4; ++ni) {
            const int col = col0 + nh + ni * 16 + l16;
            const int rbase = row0 + mh + mi * 16 + quad * 4;
            const float bv = bias[col];
            if (OUTMODE == 0) {
                float* C = (float*)Cout;
#pragma unroll
                for (int j = 0; j < 4; ++j)
                    C[(size_t)(rbase + j) * N + col] = acc[mi][ni][j] + bv;
            } else {
                if (col < 2048) {
                    ushort* C = (ushort*)Cout;
#pragma unroll
                    for (int j = 0; j < 4; ++j)
                        C[(size_t)(rbase + j) * N + col] = f2bf(acc[mi][ni][j] + bv);
                } else {
                    const int bb = rbase >> 11;
                    const int seq = rbase & 2047;
                    const int d = col - 2048;
                    ushort4 pk;
                    pk.x = f2bf(acc[mi][ni][0] + bv);
                    pk.y = f2bf(acc[mi][ni][1] + bv);
                    pk.z = f2bf(acc[mi][ni][2] + bv);
                    pk.w = f2bf(acc[mi][ni][3] + bv);
                    *(ushort4*)&Vt[(size_t)bb * 2097152 + (size_t)d * 2048 + seq] = pk;
                }
            }
        }
}

// ---------------------------------------------------------------------------
// MFMA flash attention, SPLIT-K v5: K/V/Q staged via global_load_lds
// (async direct-to-LDS, the proven R11 GEMM pattern) — the kreg/vreg
// prefetch registers are GONE. R16 counters localized the spill: live set
// (o 32 + s 16 + prefetch 16 + addr) > the 68-VGPR budget the backend
// insists on; deleting the prefetch brings the live set under budget.
// Latency hiding now comes from 12 resident waves (3 blocks/CU, LDS 49152).
// XOR chunk swizzle on the SOURCE side (slot fixed by lane order, source
// chunk = slot^(row&7)); fragment reads unchanged from R15/R16.
// REVERT TRIGGER: WRITE_SIZE >> 20 MB again -> R12 attention, stop.
// ---------------------------------------------------------------------------
__global__ __launch_bounds__(256, 2) void attn_fwd_mfma(
    const ushort* __restrict__ qkv, const ushort* __restrict__ Vt,
    ushort* __restrict__ Op, float* __restrict__ Lp) {
    const int bx = blockIdx.x;
    const int qb = bx >> 1, split = bx & 1;
    const int h = blockIdx.y, b = blockIdx.z;
    const int tid = threadIdx.x;
    const int wid = tid >> 6, lane = tid & 63, quad = lane >> 4, l16 = lane & 15;
    const int wq = wid * 32;
    const int kt0 = split * 16;
    const int r7 = l16 & 7;
    const float CEXP = 0.18033688011112042f;   // 0.125 * log2(e)

    __shared__ ushort Qs[128 * 64];
    __shared__ ushort Ks[64 * 64];    // [kpos][d], swizzled chunks
    __shared__ ushort Vts[64 * 64];   // [d][kpos], swizzled chunks
    __shared__ ushort Ps[128 * 64];   // [qrow][kpos], swizzled chunks

    // async stage Q tile (1024 chunks): LDS slot = lane order, source chunk
    // swizzled so that slot j of row r holds global chunk j^(r&7).
#pragma unroll
    for (int rep = 0; rep < 4; ++rep) {
        int c = tid + rep * 256;
        int r = c >> 3;
        int kc = (c & 7) ^ (r & 7);
        ushort* lb = &Qs[(rep * 256 + wid * 64) * 8];   // wave-uniform base
        __builtin_amdgcn_global_load_lds(
            AS1U(qkv + (size_t)(b * 2048 + qb * 128 + r) * 3072 + h * 64 + kc * 8),
            AS3U(lb), 16, 0, 0);
    }

    f32x4 o[4][2] = {};
    float l_r[2] = {0.f, 0.f};

    for (int tt = 0; tt < 16; ++tt) {
        __syncthreads();   // prev tile reads done (drains Q staging at tt=0)
        const int kt = kt0 + tt;
#pragma unroll
        for (int rep = 0; rep < 2; ++rep) {
            int c = tid + rep * 256;
            int r = c >> 3;
            int kc = (c & 7) ^ (r & 7);
            ushort* lbK = &Ks[(rep * 256 + wid * 64) * 8];
            ushort* lbV = &Vts[(rep * 256 + wid * 64) * 8];
            __builtin_amdgcn_global_load_lds(
                AS1U(qkv + (size_t)(b * 2048 + kt * 64 + r) * 3072 + 1024 + h * 64 + kc * 8),
                AS3U(lbK), 16, 0, 0);
            __builtin_amdgcn_global_load_lds(
                AS1U(Vt + (size_t)b * 2097152 + (size_t)(h * 64 + r) * 2048 + kt * 64 + kc * 8),
                AS3U(lbV), 16, 0, 0);
        }
        __syncthreads();   // drains vmcnt -> Ks/Vts visible

        f32x4 s[4][2] = {};
#pragma unroll
        for (int ks = 0; ks < 2; ++ks) {
            const int slot = ((ks * 4 + quad) ^ r7) * 8;
            s16x8 ka[4], qb_[2];
#pragma unroll
            for (int mi = 0; mi < 4; ++mi)
                ka[mi] = *(const s16x8*)&Ks[(mi * 16 + l16) * 64 + slot];
#pragma unroll
            for (int ni = 0; ni < 2; ++ni)
                qb_[ni] = *(const s16x8*)&Qs[(wq + ni * 16 + l16) * 64 + slot];
#pragma unroll
            for (int mi = 0; mi < 4; ++mi)
#pragma unroll
                for (int ni = 0; ni < 2; ++ni)
                    s[mi][ni] = __builtin_amdgcn_mfma_f32_16x16x32_bf16(
                        ka[mi], qb_[ni], s[mi][ni], 0, 0, 0);
        }

        // P write: logical kpos chunk jq = 2*mi + (quad>>1), sub-offset (quad&1)*4
#pragma unroll
        for (int ni = 0; ni < 2; ++ni)
#pragma unroll
            for (int mi = 0; mi < 4; ++mi) {
                ushort4 pk;
#pragma unroll
                for (int j = 0; j < 4; ++j) {
                    float p = exp2f(s[mi][ni][j] * CEXP);
                    l_r[ni] += p;
                    ((ushort*)&pk)[j] = f2bf(p);
                }
                const int jq = 2 * mi + (quad >> 1);
                *(ushort4*)&Ps[(wq + ni * 16 + l16) * 64 + ((jq ^ r7)) * 8 + (quad & 1) * 4] = pk;
            }

#pragma unroll
        for (int ks = 0; ks < 2; ++ks) {
            const int slot = ((ks * 4 + quad) ^ r7) * 8;
            s16x8 va[4], pb[2];
#pragma unroll
            for (int md = 0; md < 4; ++md)
                va[md] = *(const s16x8*)&Vts[(md * 16 + l16) * 64 + slot];
#pragma unroll
            for (int ni = 0; ni < 2; ++ni)
                pb[ni] = *(const s16x8*)&Ps[(wq + ni * 16 + l16) * 64 + slot];
#pragma unroll
            for (int md = 0; md < 4; ++md)
#pragma unroll
                for (int ni = 0; ni < 2; ++ni)
                    o[md][ni] = __builtin_amdgcn_mfma_f32_16x16x32_bf16(
                        va[md], pb[ni], o[md][ni], 0, 0, 0);
        }
    }

    // epilogue: write UNNORMALIZED partials.
#pragma unroll
    for (int ni = 0; ni < 2; ++ni) {
        float l = l_r[ni];
        l += __shfl_xor(l, 16);
        l += __shfl_xor(l, 32);
        const size_t row = (size_t)(b * 2048 + qb * 128 + wq + ni * 16 + l16);
        if (quad == 0)
            Lp[(size_t)split * 65536 + row * 16 + h] = l;
#pragma unroll
        for (int md = 0; md < 4; ++md) {
            ushort4 pk;
#pragma unroll
            for (int j = 0; j < 4; ++j)
                ((ushort*)&pk)[j] = f2bf(o[md][ni][j]);
            *(ushort4*)&Op[(size_t)split * 4194304 + row * 1024 + h * 64 + md * 16 + quad * 4] = pk;
        }
    }
}

// ---------------------------------------------------------------------------
// Combine the two split-K partials: ctx = (O0 + O1) / (l0 + l1).
// ---------------------------------------------------------------------------
__global__ __launch_bounds__(256) void attn_reduce(
    const ushort* __restrict__ Op, const float* __restrict__ Lp,
    ushort* __restrict__ ctx) {
    const int i = blockIdx.x * 256 + threadIdx.x;
    const size_t base = (size_t)i * 4;
    const int row = (int)(base >> 10);
    const int hh = (int)((base & 1023) >> 6);
    const float l = Lp[row * 16 + hh] + Lp[65536 + row * 16 + hh];
    const float inv = 1.f / l;
    ushort4 a = *(const ushort4*)&Op[base];
    ushort4 b = *(const ushort4*)&Op[4194304 + base];
    ushort4 o;
    o.x = f2bf((bf2f(a.x) + bf2f(b.x)) * inv);
    o.y = f2bf((bf2f(a.y) + bf2f(b.y)) * inv);
    o.z = f2bf((bf2f(a.z) + bf2f(b.z)) * inv);
    o.w = f2bf((bf2f(a.w) + bf2f(b.w)) * inv);
    *(ushort4*)&ctx[base] = o;
}

// ---------------------------------------------------------------------------
// Workspace layout (MB offsets), total 78 MB:
//   [0,16M)   A0  } reused: qkv bf16 [0,24M), Vt [24M,32M), ctx [32M,40M)
//   [16M,32M) A1  }
//   [32M,49M) H_a } dead after FFT -> Op [40M,56M), Lp [56M,57M)
//   [49M,54M) H_p
//   [54M,58M) P0   [58M,62M) P1
//   [62M,68M) WaT  [68M,70M) WpT  [70M,78M) x_bf
// ---------------------------------------------------------------------------
extern "C" void kernel_launch(void* const* d_in, const int* in_sizes, int n_in,
                              void* d_out, int out_size, void* d_ws, size_t ws_size,
                              hipStream_t stream) {
    const float* x        = (const float*)d_in[0];
    const float* attn_re  = (const float*)d_in[1];
    const float* attn_im  = (const float*)d_in[2];
    const int*   attn_idx = (const int*)d_in[3];
    const float* attn_sc  = (const float*)d_in[4];
    const float* proj_re  = (const float*)d_in[5];
    const float* proj_im  = (const float*)d_in[6];
    const int*   proj_idx = (const int*)d_in[7];
    const float* proj_sc  = (const float*)d_in[8];
    const float* attn_b   = (const float*)d_in[9];
    const float* proj_b   = (const float*)d_in[10];
    float* out = (float*)d_out;

    const size_t MB = 1048576;
    char* w = (char*)d_ws;
    float2* A0  = (float2*)(w);
    float2* A1  = (float2*)(w + 16 * MB);
    float2* Ha  = (float2*)(w + 32 * MB);
    float2* Hp  = (float2*)(w + 49 * MB);
    float2* P0  = (float2*)(w + 54 * MB);
    float2* P1  = (float2*)(w + 58 * MB);
    ushort* WaT = (ushort*)(w + 62 * MB);
    ushort* WpT = (ushort*)(w + 68 * MB);
    ushort* x_bf= (ushort*)(w + 70 * MB);
    ushort* qkvb= (ushort*)(w);
    ushort* Vt  = (ushort*)(w + 24 * MB);
    ushort* ctx = (ushort*)(w + 32 * MB);
    ushort* Op  = (ushort*)(w + 40 * MB);   // 2 x 8MB bf16 partial O
    float*  Lp  = (float*)(w + 56 * MB);    // 2 x 256KB fp32 partial l

    x_to_bf16<<<4096, 256, 0, stream>>>(x, x_bf, 1048576);

    // one memset covers Ha [32M,~48.8M) and Hp [49M,~53.2M) (gap is dead)
    hipMemsetAsync(w + 32 * MB, 0, 22 * MB, stream);
    scatter_half2<<<(ATTN_KEEP_C + PROJ_KEEP_C) / 256, 256, 0, stream>>>(
        attn_re, attn_im, attn_idx, Ha, proj_re, proj_im, proj_idx, Hp);

    // ---- attn iFFT: pack -> A0; 3 fused radix-64 passes + 1 radix-8 ----
    pack_z<<<ATTN_NC / 256, 256, 0, stream>>>(Ha, A0, ATTN_NC, (float)(2.0 * M_PI / ATTN_PAD_C));
    fft_stage_r64<<<(ATTN_NC / 8) / 256, 256, 0, stream>>>(A0, A1, 0,  ATTN_NC >> 3);
    fft_stage_r64<<<(ATTN_NC / 8) / 256, 256, 0, stream>>>(A1, A0, 6,  ATTN_NC >> 9);
    fft_stage_r64<<<(ATTN_NC / 8) / 256, 256, 0, stream>>>(A0, A1, 12, ATTN_NC >> 15);
    fft_stage_r8 <<<(ATTN_NC / 8) / 256, 256, 0, stream>>>(A1, A0, 18, 1,
        (float)(M_PI / 4.0), ATTN_NC / 8);
    transpose_wz_bf16<<<dim3(3072 / 32, 1024 / 32), 256, 0, stream>>>(
        A0, WaT, 1024, 3072, 1.f / ATTN_PAD_C, attn_sc);

    // ---- proj iFFT: pack -> P0; r2 + 3 fused radix-64 passes ----
    pack_z<<<PROJ_NC / 256, 256, 0, stream>>>(Hp, P0, PROJ_NC, (float)(2.0 * M_PI / PROJ_PAD_C));
    fft_stage<<<(PROJ_NC / 2) / 256, 256, 0, stream>>>(P0, P1, 0, PROJ_NC / 2, PROJ_NC / 2);
    fft_stage_r64<<<(PROJ_NC / 8) / 256, 256, 0, stream>>>(P1, P0, 1,  PROJ_NC >> 4);
    fft_stage_r64<<<(PROJ_NC / 8) / 256, 256, 0, stream>>>(P0, P1, 7,  PROJ_NC >> 10);
    fft_stage_r64<<<(PROJ_NC / 8) / 256, 256, 0, stream>>>(P1, P0, 13, PROJ_NC >> 16);
    transpose_wz_bf16<<<dim3(1024 / 32, 1024 / 32), 256, 0, stream>>>(
        P0, WpT, 1024, 1024, 1.f / PROJ_PAD_C, proj_sc);

    // qkv = x @ Wa + bias (bf16 out; V third written transposed into Vt)
    gemm_bt_mfma<1><<<dim3(3072 / 128, 4096 / 128), 256, 0, stream>>>(
        x_bf, WaT, attn_b, qkvb, Vt, 4096, 3072, 1024);

    // attention: split-K, async LDS staging, then reduce
    attn_fwd_mfma<<<dim3(SEQ_C / 64, N_HEADC, BATCH_C), 256, 0, stream>>>(qkvb, Vt, Op, Lp);
    attn_reduce<<<4096, 256, 0, stream>>>(Op, Lp, ctx);

    gemm_bt_mfma<0><<<dim3(1024 / 128, 4096 / 128), 256, 0, stream>>>(
        ctx, WpT, proj_b, out, (ushort*)nullptr, 4096, 1024, 1024);
}